// Round 11
// baseline (586.097 us; speedup 1.0000x reference)
//
#include <hip/hip_runtime.h>
#include <hip/hip_fp16.h>

#define IN_F 256
#define OUT_F 256
#define HALF_F 128
#define RPB_SHIFT 9          // 512 rows per bin
#define RPB (1 << RPB_SHIFT)
#define NBINS_MAX 256
#define TILE_E 4096
#define XS_PAD 40            // LDS row stride in bf16 (80 B; 16B-aligned, bank-spread)
#define A2_CHUNKS 8

using bf16x8 = __attribute__((ext_vector_type(8))) short;
using bf16x4 = __attribute__((ext_vector_type(4))) short;
using f32x4  = __attribute__((ext_vector_type(4))) float;
using ull    = unsigned long long;

__device__ inline short bf16rne(float f) {
    unsigned u = __float_as_uint(f);
    u = u + 0x7FFFu + ((u >> 16) & 1u);
    return (short)(u >> 16);
}
__device__ inline unsigned pack_half2(float a, float b) {
    __half2 h = __floats2half2_rn(a, b);
    return *reinterpret_cast<unsigned*>(&h);
}

// ---------------------------------------------------------------------------
// wt[n][k] = bf16(w[k][n])
// ---------------------------------------------------------------------------
__global__ __launch_bounds__(256) void convert_wt_kernel(
    const float* __restrict__ w, short* __restrict__ wt)
{
    const int idx = blockIdx.x * blockDim.x + threadIdx.x;
    const int c = idx >> 8, k = idx & 255;
    wt[(size_t)c * IN_F + k] = bf16rne(w[(size_t)k * OUT_F + c]);
}

// ---------------------------------------------------------------------------
// MFMA GEMM, LDS-staged + double-buffered, BM=32 (unchanged from R8)
// ---------------------------------------------------------------------------
__global__ __launch_bounds__(256) void mfma_gemm_kernel(
    const float* __restrict__ x, const short* __restrict__ wt,
    __half* __restrict__ supA, __half* __restrict__ supB, int M)
{
    __shared__ short xs[2][32][XS_PAD];

    const int t    = threadIdx.x;
    const int lane = t & 63;
    const int wid  = t >> 6;
    const int l15  = lane & 15;
    const int l4   = lane >> 4;
    const int rowbase = blockIdx.x * 32;
    const int cbase   = wid * 64;

    const int srow = t >> 3;
    const int sks  = (t & 7) * 4;
    int grow = rowbase + srow; if (grow > M - 1) grow = M - 1;
    const float* xsrc = x + (size_t)grow * IN_F + sks;

    f32x4 acc[2][4];
#pragma unroll
    for (int rt = 0; rt < 2; ++rt)
#pragma unroll
        for (int ct = 0; ct < 4; ++ct)
            acc[rt][ct] = (f32x4){0.f, 0.f, 0.f, 0.f};

    const short* wp[4];
#pragma unroll
    for (int ct = 0; ct < 4; ++ct)
        wp[ct] = wt + (size_t)(cbase + ct * 16 + l15) * IN_F + l4 * 8;

    {
        const float4 f = *(const float4*)xsrc;
        bf16x4 v;
        v[0] = bf16rne(f.x); v[1] = bf16rne(f.y);
        v[2] = bf16rne(f.z); v[3] = bf16rne(f.w);
        *(bf16x4*)&xs[0][srow][sks] = v;
    }
    __syncthreads();

#pragma unroll
    for (int k0 = 0; k0 < 8; ++k0) {
        const int cur = k0 & 1;

        float4 nf;
        if (k0 < 7) nf = *(const float4*)(xsrc + (k0 + 1) * 32);

        bf16x8 b[4];
#pragma unroll
        for (int ct = 0; ct < 4; ++ct)
            b[ct] = *(const bf16x8*)(wp[ct] + k0 * 32);

        bf16x8 a[2];
#pragma unroll
        for (int rt = 0; rt < 2; ++rt)
            a[rt] = *(const bf16x8*)&xs[cur][rt * 16 + l15][l4 * 8];

#pragma unroll
        for (int rt = 0; rt < 2; ++rt)
#pragma unroll
            for (int ct = 0; ct < 4; ++ct)
                acc[rt][ct] = __builtin_amdgcn_mfma_f32_16x16x32_bf16(
                    b[ct], a[rt], acc[rt][ct], 0, 0, 0);

        if (k0 < 7) {
            bf16x4 v;
            v[0] = bf16rne(nf.x); v[1] = bf16rne(nf.y);
            v[2] = bf16rne(nf.z); v[3] = bf16rne(nf.w);
            *(bf16x4*)&xs[cur ^ 1][srow][sks] = v;
        }
        __syncthreads();
    }

    __half* dst = (wid < 2) ? supA : supB;
    const int fbase = (wid & 1) * 64;
#pragma unroll
    for (int rt = 0; rt < 2; ++rt) {
        const int r = rowbase + rt * 16 + l15;
        if (r >= M) continue;
#pragma unroll
        for (int ct = 0; ct < 4; ++ct) {
            uint2 pk;
            pk.x = pack_half2(acc[rt][ct][0], acc[rt][ct][1]);
            pk.y = pack_half2(acc[rt][ct][2], acc[rt][ct][3]);
            *(uint2*)(dst + (size_t)r * HALF_F + fbase + ct * 16 + l4 * 4) = pk;
        }
    }
}

// ---------------------------------------------------------------------------
// per-row edge counts (non-returning atomics, ~32/addr — measured cheap)
// ---------------------------------------------------------------------------
__global__ __launch_bounds__(256) void count_kernel(
    const int* __restrict__ ei, int* __restrict__ counts, int E)
{
    const int e = blockIdx.x * blockDim.x + threadIdx.x;
    if (e < E) atomicAdd(&counts[__builtin_nontemporal_load(ei + e)], 1);
}

// ---------------------------------------------------------------------------
// a1a: per-tile bin histogram -> thist[t][b]
// ---------------------------------------------------------------------------
__global__ __launch_bounds__(256) void a1a_hist_kernel(
    const int* __restrict__ ei, int* __restrict__ thist, int E)
{
    __shared__ int hist[NBINS_MAX];
    const int tid = threadIdx.x;
    hist[tid] = 0;
    __syncthreads();
    const int base = blockIdx.x * TILE_E;
#pragma unroll
    for (int i = 0; i < TILE_E / 256; ++i) {
        const int e = base + i * 256 + tid;
        if (e < E)
            atomicAdd(&hist[__builtin_nontemporal_load(ei + e) >> RPB_SHIFT], 1);
    }
    __syncthreads();
    thist[(size_t)blockIdx.x * NBINS_MAX + tid] = hist[tid];
}

// per-bin exclusive scan over tiles, in place; emits btot[b]
__global__ __launch_bounds__(256) void tile_scan_kernel(
    int* __restrict__ thist, int* __restrict__ btot, int T)
{
    const int b   = blockIdx.x;
    const int tid = threadIdx.x;
    __shared__ int s[256];
    int carry = 0;
    for (int c0 = 0; c0 < T; c0 += 256) {
        const int t = c0 + tid;
        const int v = (t < T) ? thist[(size_t)t * NBINS_MAX + b] : 0;
        s[tid] = v;
        __syncthreads();
        for (int d = 1; d < 256; d <<= 1) {
            const int u = (tid >= d) ? s[tid - d] : 0;
            __syncthreads();
            s[tid] += u;
            __syncthreads();
        }
        const int total = s[255];
        if (t < T) thist[(size_t)t * NBINS_MAX + b] = carry + s[tid] - v;
        carry += total;
        __syncthreads();
    }
    if (tid == 0) btot[b] = carry;
}

// exclusive scan of bin totals (1 block)
__global__ __launch_bounds__(NBINS_MAX) void bin_scan_kernel(
    const int* __restrict__ btot, int* __restrict__ bstart, int nbins)
{
    __shared__ int s[NBINS_MAX];
    const int tid = threadIdx.x;
    const int v = (tid < nbins) ? btot[tid] : 0;
    s[tid] = v;
    __syncthreads();
    for (int d = 1; d < NBINS_MAX; d <<= 1) {
        const int u = (tid >= d) ? s[tid - d] : 0;
        __syncthreads();
        s[tid] += u;
        __syncthreads();
    }
    bstart[tid] = s[tid] - v;
}

// ---------------------------------------------------------------------------
// row starts: cursor_start[row] = bstart[bin] + in-bin exclusive scan of
// counts; also initializes the live cursors. One block per bin.
// ---------------------------------------------------------------------------
__global__ __launch_bounds__(256) void row_scan_kernel(
    const int* __restrict__ counts, const int* __restrict__ bstart,
    int* __restrict__ cur_start, int* __restrict__ cur_live, int M)
{
    const int bin  = blockIdx.x;
    const int base = bin << RPB_SHIFT;
    const int tid  = threadIdx.x;
    const int r0 = base + 2 * tid, r1 = r0 + 1;
    const int c0 = (r0 < M) ? counts[r0] : 0;
    const int c1 = (r1 < M) ? counts[r1] : 0;
    __shared__ int s[256];
    const int own = c0 + c1;
    s[tid] = own;
    __syncthreads();
    for (int d = 1; d < 256; d <<= 1) {
        const int u = (tid >= d) ? s[tid - d] : 0;
        __syncthreads();
        s[tid] += u;
        __syncthreads();
    }
    const int excl = s[tid] - own + bstart[bin];
    if (r0 < M) { cur_start[r0] = excl;      cur_live[r0] = excl; }
    if (r1 < M) { cur_start[r1] = excl + c0; cur_live[r1] = excl + c0; }
}

// ---------------------------------------------------------------------------
// a1b: deterministic binned scatter. Entry = (w:32 | col:17 | rowLo:9)
// ---------------------------------------------------------------------------
__global__ __launch_bounds__(256) void a1b_scatter_kernel(
    const int* __restrict__ ei, const float* __restrict__ ew,
    const int* __restrict__ bstart, const int* __restrict__ thist,
    ull* __restrict__ tscw, int E)
{
    __shared__ int hist[NBINS_MAX];
    __shared__ int rbase[NBINS_MAX];
    const int tid = threadIdx.x;
    hist[tid]  = 0;
    rbase[tid] = bstart[tid] + thist[(size_t)blockIdx.x * NBINS_MAX + tid];
    __syncthreads();
    const int base = blockIdx.x * TILE_E;
#pragma unroll
    for (int i = 0; i < TILE_E / 256; ++i) {
        const int e = base + i * 256 + tid;
        if (e < E) {
            const int      row = __builtin_nontemporal_load(ei + e);
            const int      col = __builtin_nontemporal_load(ei + E + e);
            const unsigned wb  = __builtin_nontemporal_load((const unsigned*)ew + e);
            const int b   = row >> RPB_SHIFT;
            const int rnk = atomicAdd(&hist[b], 1);
            tscw[rbase[b] + rnk] = ((ull)wb << 32) |
                                   ((unsigned)col << RPB_SHIFT) |
                                   (unsigned)(row & (RPB - 1));
        }
    }
}

// ---------------------------------------------------------------------------
// a2: row-placement scatter, 8 chunks/bin (1568 blocks — no CU starvation).
// Global live cursors (~32 contenders/addr). Final entry = 4 B:
//   (w:15-bit fixed << 17) | col:17.  Stores land in the bin's ~65 KB
//   region -> lines fill in L2.
// ---------------------------------------------------------------------------
__global__ __launch_bounds__(256) void a2_scatter_kernel(
    const ull* __restrict__ tscw, const int* __restrict__ bstart,
    const int* __restrict__ btot, int* __restrict__ cur_live,
    unsigned* __restrict__ scw4)
{
    const int b  = blockIdx.x / A2_CHUNKS;
    const int c  = blockIdx.x % A2_CHUNKS;
    const int n  = btot[b];
    const int s0 = bstart[b];
    const int i0 = (int)(((long long)n * c) / A2_CHUNKS);
    const int i1 = (int)(((long long)n * (c + 1)) / A2_CHUNKS);
    for (int i = i0 + (int)threadIdx.x; i < i1; i += 256) {
        const ull en = __builtin_nontemporal_load(tscw + s0 + i);
        const int row = (b << RPB_SHIFT) | (int)(en & (RPB - 1));
        const unsigned col = (unsigned)((en >> RPB_SHIFT) & 0x1FFFFu);
        const float wf = __uint_as_float((unsigned)(en >> 32));
        const unsigned w15 = (unsigned)(wf * 32767.0f + 0.5f);
        const int pos = atomicAdd(&cur_live[row], 1);
        scw4[pos] = (w15 << 17) | col;
    }
}

// ---------------------------------------------------------------------------
// Pull, feature-half pass: wave = 2 rows x 32 lanes; 4 B edge entries;
// 8-wide gather ILP.
// ---------------------------------------------------------------------------
__global__ __launch_bounds__(256) void pull_half_kernel(
    const int* __restrict__ counts, const int* __restrict__ cur_start,
    const unsigned* __restrict__ scw4, const __half* __restrict__ suph,
    const float* __restrict__ biash, float* __restrict__ outh, int M)
{
    const int wv  = blockIdx.x * 4 + (threadIdx.x >> 6);
    const int row = wv * 2 + ((threadIdx.x >> 5) & 1);
    if (row >= M) return;
    const int l = threadIdx.x & 31;

    const int cnt   = counts[row];
    const int start = cur_start[row];

    float4 acc = *(const float4*)(biash + l * 4);

#define GATHER_FMA_H(pe)                                                      \
    {                                                                         \
        const int   c  = (int)((pe) & 0x1FFFFu);                              \
        const float wj = (float)((pe) >> 17) * (1.0f / 32767.0f);             \
        const uint2 v = *(const uint2*)(suph + (size_t)c * HALF_F + l * 4);   \
        const float2 f0 = __half22float2(*(const __half2*)&v.x);              \
        const float2 f1 = __half22float2(*(const __half2*)&v.y);              \
        acc.x = fmaf(wj, f0.x, acc.x); acc.y = fmaf(wj, f0.y, acc.y);         \
        acc.z = fmaf(wj, f1.x, acc.z); acc.w = fmaf(wj, f1.y, acc.w);         \
    }

    for (int j0 = 0; j0 < cnt; j0 += 32) {
        unsigned pr = 0u;
        if (j0 + l < cnt)
            pr = __builtin_nontemporal_load(scw4 + start + j0 + l);
        const int m = min(32, cnt - j0);

        int j = 0;
        for (; j + 8 <= m; j += 8) {
            const unsigned p0 = __shfl(pr, j, 32),     p1 = __shfl(pr, j + 1, 32);
            const unsigned p2 = __shfl(pr, j + 2, 32), p3 = __shfl(pr, j + 3, 32);
            const unsigned p4 = __shfl(pr, j + 4, 32), p5 = __shfl(pr, j + 5, 32);
            const unsigned p6 = __shfl(pr, j + 6, 32), p7 = __shfl(pr, j + 7, 32);
            GATHER_FMA_H(p0); GATHER_FMA_H(p1); GATHER_FMA_H(p2); GATHER_FMA_H(p3);
            GATHER_FMA_H(p4); GATHER_FMA_H(p5); GATHER_FMA_H(p6); GATHER_FMA_H(p7);
        }
        for (; j < m; ++j) {
            const unsigned p = __shfl(pr, j, 32);
            GATHER_FMA_H(p);
        }
    }
#undef GATHER_FMA_H

    f32x4 o; o[0] = acc.x; o[1] = acc.y; o[2] = acc.z; o[3] = acc.w;
    __builtin_nontemporal_store(o, (f32x4*)(outh + (size_t)row * OUT_F + l * 4));
}

// --------------------------- fallback path ---------------------------
__global__ __launch_bounds__(256) void bias_init_kernel(
    float* __restrict__ out, const float* __restrict__ bias, int total4)
{
    const float4* b4 = (const float4*)bias;
    float4* o4 = (float4*)out;
    for (int i = blockIdx.x * blockDim.x + threadIdx.x; i < total4;
         i += gridDim.x * blockDim.x)
        o4[i] = b4[i & 63];
}

__global__ __launch_bounds__(256) void edge_scatter_kernel(
    const int* __restrict__ ei, const float* __restrict__ ew,
    const __half* __restrict__ supA, const __half* __restrict__ supB,
    float* __restrict__ out, int E)
{
    const int e = blockIdx.x * 4 + (threadIdx.x >> 6);
    if (e >= E) return;
    const int lane = threadIdx.x & 63;
    const int   row = ei[e];
    const int   col = ei[E + e];
    const float wgt = ew[e];
    const __half* src = (lane < 32) ? supA : supB;
    const int fl = (lane & 31) * 4;
    const uint2 v = *(const uint2*)(src + (size_t)col * HALF_F + fl);
    const float2 f0 = __half22float2(*(const __half2*)&v.x);
    const float2 f1 = __half22float2(*(const __half2*)&v.y);
    float* o = out + (size_t)row * OUT_F + (lane >> 5) * HALF_F + fl;
    unsafeAtomicAdd(o + 0, wgt * f0.x);
    unsafeAtomicAdd(o + 1, wgt * f0.y);
    unsafeAtomicAdd(o + 2, wgt * f1.x);
    unsafeAtomicAdd(o + 3, wgt * f1.y);
}

// ---------------------------------------------------------------------------
extern "C" void kernel_launch(void* const* d_in, const int* in_sizes, int n_in,
                              void* d_out, int out_size, void* d_ws, size_t ws_size,
                              hipStream_t stream)
{
    const float* x    = (const float*)d_in[0];
    const int*   ei   = (const int*)d_in[1];
    const float* ew   = (const float*)d_in[2];
    const float* w    = (const float*)d_in[3];
    const float* bias = (const float*)d_in[4];
    float* out = (float*)d_out;

    const int M = in_sizes[0] / IN_F;   // 100000
    const int E = in_sizes[2];          // 3,200,000
    const int nbins = (M + RPB - 1) >> RPB_SHIFT;        // 196
    const int T     = (E + TILE_E - 1) / TILE_E;         // 782

    // workspace layout
    char* p = (char*)d_ws;
    const size_t suph_b   = (((size_t)M * HALF_F * sizeof(__half)) + 255) & ~255ull;
    const size_t counts_b = ((size_t)M * 4 + 255) & ~255ull;
    const size_t btot_b   = NBINS_MAX * 4;
    const size_t cstart_b = counts_b;
    const size_t clive_b  = counts_b;
    const size_t bstart_b = NBINS_MAX * 4;
    const size_t thist_b  = (((size_t)T * NBINS_MAX * 4) + 255) & ~255ull;
    const size_t scw4_b   = ((size_t)E * 4 + 255) & ~255ull;
    const size_t tscw_b   = ((size_t)E * 8 + 255) & ~255ull;
    const size_t wt_b     = (size_t)IN_F * OUT_F * sizeof(short);
    const size_t need     = 2 * suph_b + counts_b + btot_b + cstart_b + clive_b
                          + bstart_b + thist_b + scw4_b + tscw_b + wt_b;

    __half*   supA    = (__half*)p;            p += suph_b;
    __half*   supB    = (__half*)p;            p += suph_b;
    int*      counts  = (int*)p;               p += counts_b;
    int*      btot    = (int*)p;               p += btot_b;
    int*      cstart  = (int*)p;               p += cstart_b;
    int*      clive   = (int*)p;               p += clive_b;
    int*      bstart  = (int*)p;               p += bstart_b;
    int*      thist   = (int*)p;               p += thist_b;
    unsigned* scw4    = (unsigned*)p;          p += scw4_b;
    ull*      tscw    = (ull*)p;               p += tscw_b;
    short*    wtb     = (short*)p;

    // 1) wt = bf16(w^T); supA/B = fp16(x @ W) via LDS-staged MFMA
    convert_wt_kernel<<<(IN_F * OUT_F) / 256, 256, 0, stream>>>(w, wtb);
    mfma_gemm_kernel<<<(M + 31) / 32, 256, 0, stream>>>(x, wtb, supA, supB, M);

    if (ws_size >= need) {
        // 2) CSR build
        hipMemsetAsync(counts, 0, (size_t)M * 4, stream);
        count_kernel<<<(E + 255) / 256, 256, 0, stream>>>(ei, counts, E);
        a1a_hist_kernel<<<T, 256, 0, stream>>>(ei, thist, E);
        tile_scan_kernel<<<nbins, 256, 0, stream>>>(thist, btot, T);
        bin_scan_kernel<<<1, NBINS_MAX, 0, stream>>>(btot, bstart, nbins);
        row_scan_kernel<<<nbins, 256, 0, stream>>>(counts, bstart, cstart, clive, M);
        a1b_scatter_kernel<<<T, 256, 0, stream>>>(ei, ew, bstart, thist, tscw, E);
        a2_scatter_kernel<<<nbins * A2_CHUNKS, 256, 0, stream>>>(
            tscw, bstart, btot, clive, scw4);
        // 3) pull, two feature-half passes
        const int pblocks = ((M + 1) / 2 + 3) / 4;
        pull_half_kernel<<<pblocks, 256, 0, stream>>>(
            counts, cstart, scw4, supA, bias, out, M);
        pull_half_kernel<<<pblocks, 256, 0, stream>>>(
            counts, cstart, scw4, supB, bias + HALF_F, out + HALF_F, M);
    } else {
        const int total4 = M * OUT_F / 4;
        bias_init_kernel<<<2048, 256, 0, stream>>>(out, bias, total4);
        edge_scatter_kernel<<<(E + 3) / 4, 256, 0, stream>>>(ei, ew, supA, supB, out, E);
    }
}

// Round 12
// 408.367 us; speedup vs baseline: 1.4352x; 1.4352x over previous
//
#include <hip/hip_runtime.h>
#include <hip/hip_fp16.h>

#define IN_F 256
#define OUT_F 256
#define HALF_F 128
#define RPB_SHIFT 9          // 512 rows per bin
#define RPB (1 << RPB_SHIFT)
#define NBINS_MAX 256
#define TILE_E 4096
#define XS_PAD 40            // LDS row stride in bf16 (80 B; 16B-aligned, bank-spread)

using bf16x8 = __attribute__((ext_vector_type(8))) short;
using bf16x4 = __attribute__((ext_vector_type(4))) short;
using f32x4  = __attribute__((ext_vector_type(4))) float;
using ull    = unsigned long long;

__device__ inline short bf16rne(float f) {
    unsigned u = __float_as_uint(f);
    u = u + 0x7FFFu + ((u >> 16) & 1u);
    return (short)(u >> 16);
}
__device__ inline unsigned pack_half2(float a, float b) {
    __half2 h = __floats2half2_rn(a, b);
    return *reinterpret_cast<unsigned*>(&h);
}

// ---------------------------------------------------------------------------
// wt[n][k] = bf16(w[k][n])
// ---------------------------------------------------------------------------
__global__ __launch_bounds__(256) void convert_wt_kernel(
    const float* __restrict__ w, short* __restrict__ wt)
{
    const int idx = blockIdx.x * blockDim.x + threadIdx.x;
    const int c = idx >> 8, k = idx & 255;
    wt[(size_t)c * IN_F + k] = bf16rne(w[(size_t)k * OUT_F + c]);
}

// ---------------------------------------------------------------------------
// MFMA GEMM, LDS-staged + double-buffered, BM=32 (R8-verified)
// ---------------------------------------------------------------------------
__global__ __launch_bounds__(256) void mfma_gemm_kernel(
    const float* __restrict__ x, const short* __restrict__ wt,
    __half* __restrict__ supA, __half* __restrict__ supB, int M)
{
    __shared__ short xs[2][32][XS_PAD];

    const int t    = threadIdx.x;
    const int lane = t & 63;
    const int wid  = t >> 6;
    const int l15  = lane & 15;
    const int l4   = lane >> 4;
    const int rowbase = blockIdx.x * 32;
    const int cbase   = wid * 64;

    const int srow = t >> 3;
    const int sks  = (t & 7) * 4;
    int grow = rowbase + srow; if (grow > M - 1) grow = M - 1;
    const float* xsrc = x + (size_t)grow * IN_F + sks;

    f32x4 acc[2][4];
#pragma unroll
    for (int rt = 0; rt < 2; ++rt)
#pragma unroll
        for (int ct = 0; ct < 4; ++ct)
            acc[rt][ct] = (f32x4){0.f, 0.f, 0.f, 0.f};

    const short* wp[4];
#pragma unroll
    for (int ct = 0; ct < 4; ++ct)
        wp[ct] = wt + (size_t)(cbase + ct * 16 + l15) * IN_F + l4 * 8;

    {
        const float4 f = *(const float4*)xsrc;
        bf16x4 v;
        v[0] = bf16rne(f.x); v[1] = bf16rne(f.y);
        v[2] = bf16rne(f.z); v[3] = bf16rne(f.w);
        *(bf16x4*)&xs[0][srow][sks] = v;
    }
    __syncthreads();

#pragma unroll
    for (int k0 = 0; k0 < 8; ++k0) {
        const int cur = k0 & 1;

        float4 nf;
        if (k0 < 7) nf = *(const float4*)(xsrc + (k0 + 1) * 32);

        bf16x8 b[4];
#pragma unroll
        for (int ct = 0; ct < 4; ++ct)
            b[ct] = *(const bf16x8*)(wp[ct] + k0 * 32);

        bf16x8 a[2];
#pragma unroll
        for (int rt = 0; rt < 2; ++rt)
            a[rt] = *(const bf16x8*)&xs[cur][rt * 16 + l15][l4 * 8];

#pragma unroll
        for (int rt = 0; rt < 2; ++rt)
#pragma unroll
            for (int ct = 0; ct < 4; ++ct)
                acc[rt][ct] = __builtin_amdgcn_mfma_f32_16x16x32_bf16(
                    b[ct], a[rt], acc[rt][ct], 0, 0, 0);

        if (k0 < 7) {
            bf16x4 v;
            v[0] = bf16rne(nf.x); v[1] = bf16rne(nf.y);
            v[2] = bf16rne(nf.z); v[3] = bf16rne(nf.w);
            *(bf16x4*)&xs[cur ^ 1][srow][sks] = v;
        }
        __syncthreads();
    }

    __half* dst = (wid < 2) ? supA : supB;
    const int fbase = (wid & 1) * 64;
#pragma unroll
    for (int rt = 0; rt < 2; ++rt) {
        const int r = rowbase + rt * 16 + l15;
        if (r >= M) continue;
#pragma unroll
        for (int ct = 0; ct < 4; ++ct) {
            uint2 pk;
            pk.x = pack_half2(acc[rt][ct][0], acc[rt][ct][1]);
            pk.y = pack_half2(acc[rt][ct][2], acc[rt][ct][3]);
            *(uint2*)(dst + (size_t)r * HALF_F + fbase + ct * 16 + l4 * 4) = pk;
        }
    }
}

// ---------------------------------------------------------------------------
// a1a: per-tile bin histogram -> thist[t][b]   (LDS atomics only)
// ---------------------------------------------------------------------------
__global__ __launch_bounds__(256) void a1a_hist_kernel(
    const int* __restrict__ ei, int* __restrict__ thist, int E)
{
    __shared__ int hist[NBINS_MAX];
    const int tid = threadIdx.x;
    hist[tid] = 0;
    __syncthreads();
    const int base = blockIdx.x * TILE_E;
#pragma unroll
    for (int i = 0; i < TILE_E / 256; ++i) {
        const int e = base + i * 256 + tid;
        if (e < E)
            atomicAdd(&hist[__builtin_nontemporal_load(ei + e) >> RPB_SHIFT], 1);
    }
    __syncthreads();
    thist[(size_t)blockIdx.x * NBINS_MAX + tid] = hist[tid];
}

// per-bin exclusive scan over tiles, in place; emits btot[b]
__global__ __launch_bounds__(256) void tile_scan_kernel(
    int* __restrict__ thist, int* __restrict__ btot, int T)
{
    const int b   = blockIdx.x;
    const int tid = threadIdx.x;
    __shared__ int s[256];
    int carry = 0;
    for (int c0 = 0; c0 < T; c0 += 256) {
        const int t = c0 + tid;
        const int v = (t < T) ? thist[(size_t)t * NBINS_MAX + b] : 0;
        s[tid] = v;
        __syncthreads();
        for (int d = 1; d < 256; d <<= 1) {
            const int u = (tid >= d) ? s[tid - d] : 0;
            __syncthreads();
            s[tid] += u;
            __syncthreads();
        }
        const int total = s[255];
        if (t < T) thist[(size_t)t * NBINS_MAX + b] = carry + s[tid] - v;
        carry += total;
        __syncthreads();
    }
    if (tid == 0) btot[b] = carry;
}

// exclusive scan of bin totals (1 block)
__global__ __launch_bounds__(NBINS_MAX) void bin_scan_kernel(
    const int* __restrict__ btot, int* __restrict__ bstart, int nbins)
{
    __shared__ int s[NBINS_MAX];
    const int tid = threadIdx.x;
    const int v = (tid < nbins) ? btot[tid] : 0;
    s[tid] = v;
    __syncthreads();
    for (int d = 1; d < NBINS_MAX; d <<= 1) {
        const int u = (tid >= d) ? s[tid - d] : 0;
        __syncthreads();
        s[tid] += u;
        __syncthreads();
    }
    bstart[tid] = s[tid] - v;
}

// ---------------------------------------------------------------------------
// a1b: deterministic binned scatter. Entry = (w:32 | col:17 | rowLo:9)
// ---------------------------------------------------------------------------
__global__ __launch_bounds__(256) void a1b_scatter_kernel(
    const int* __restrict__ ei, const float* __restrict__ ew,
    const int* __restrict__ bstart, const int* __restrict__ thist,
    ull* __restrict__ tscw, int E)
{
    __shared__ int hist[NBINS_MAX];
    __shared__ int rbase[NBINS_MAX];
    const int tid = threadIdx.x;
    hist[tid]  = 0;
    rbase[tid] = bstart[tid] + thist[(size_t)blockIdx.x * NBINS_MAX + tid];
    __syncthreads();
    const int base = blockIdx.x * TILE_E;
#pragma unroll
    for (int i = 0; i < TILE_E / 256; ++i) {
        const int e = base + i * 256 + tid;
        if (e < E) {
            const int      row = __builtin_nontemporal_load(ei + e);
            const int      col = __builtin_nontemporal_load(ei + E + e);
            const unsigned wb  = __builtin_nontemporal_load((const unsigned*)ew + e);
            const int b   = row >> RPB_SHIFT;
            const int rnk = atomicAdd(&hist[b], 1);
            tscw[rbase[b] + rnk] = ((ull)wb << 32) |
                                   ((unsigned)col << RPB_SHIFT) |
                                   (unsigned)(row & (RPB - 1));
        }
    }
}

// ---------------------------------------------------------------------------
// a2: in-bin LDS counting sort (512 threads, 1 row/thread). Emits row-sorted
// 4B entries (w15 | col17), counts[row], cursor[row]. Zero global atomics.
// ---------------------------------------------------------------------------
__global__ __launch_bounds__(512) void a2_sort_kernel(
    const ull* __restrict__ tscw, const int* __restrict__ bstart,
    const int* __restrict__ btot, int* __restrict__ counts,
    int* __restrict__ cursor, unsigned* __restrict__ scw4, int M)
{
    const int b   = blockIdx.x;
    const int tid = threadIdx.x;
    const int n   = btot[b];
    const int s0  = bstart[b];

    __shared__ int hist[RPB];
    __shared__ int cur[RPB];
    __shared__ int s[RPB];

    hist[tid] = 0;
    __syncthreads();

    for (int i = tid; i < n; i += 512)
        atomicAdd(&hist[(int)(__builtin_nontemporal_load(tscw + s0 + i) & (RPB - 1))], 1);
    __syncthreads();

    // exclusive scan of 512 (Hillis-Steele, 512 threads)
    const int own = hist[tid];
    s[tid] = own;
    __syncthreads();
    for (int d = 1; d < RPB; d <<= 1) {
        const int u = (tid >= d) ? s[tid - d] : 0;
        __syncthreads();
        s[tid] += u;
        __syncthreads();
    }
    const int excl = s[tid] - own;

    const int grow = (b << RPB_SHIFT) + tid;
    if (grow < M) { counts[grow] = own; cursor[grow] = s0 + excl; }
    cur[tid] = s0 + excl;
    __syncthreads();

    for (int i = tid; i < n; i += 512) {
        const ull en = __builtin_nontemporal_load(tscw + s0 + i);
        const int key = (int)(en & (RPB - 1));
        const unsigned col = (unsigned)((en >> RPB_SHIFT) & 0x1FFFFu);
        const float wf = __uint_as_float((unsigned)(en >> 32));
        const unsigned w15 = (unsigned)(wf * 32767.0f + 0.5f);
        const int pos = atomicAdd(&cur[key], 1);
        scw4[pos] = (w15 << 17) | col;
    }
}

// ---------------------------------------------------------------------------
// Pull, feature-half pass: wave = 2 rows x 32 lanes; 4 B entries; 8-wide ILP.
// ---------------------------------------------------------------------------
__global__ __launch_bounds__(256) void pull_half_kernel(
    const int* __restrict__ counts, const int* __restrict__ cur_start,
    const unsigned* __restrict__ scw4, const __half* __restrict__ suph,
    const float* __restrict__ biash, float* __restrict__ outh, int M)
{
    const int wv  = blockIdx.x * 4 + (threadIdx.x >> 6);
    const int row = wv * 2 + ((threadIdx.x >> 5) & 1);
    if (row >= M) return;
    const int l = threadIdx.x & 31;

    const int cnt   = counts[row];
    const int start = cur_start[row];

    float4 acc = *(const float4*)(biash + l * 4);

#define GATHER_FMA_H(pe)                                                      \
    {                                                                         \
        const int   c  = (int)((pe) & 0x1FFFFu);                              \
        const float wj = (float)((pe) >> 17) * (1.0f / 32767.0f);             \
        const uint2 v = *(const uint2*)(suph + (size_t)c * HALF_F + l * 4);   \
        const float2 f0 = __half22float2(*(const __half2*)&v.x);              \
        const float2 f1 = __half22float2(*(const __half2*)&v.y);              \
        acc.x = fmaf(wj, f0.x, acc.x); acc.y = fmaf(wj, f0.y, acc.y);         \
        acc.z = fmaf(wj, f1.x, acc.z); acc.w = fmaf(wj, f1.y, acc.w);         \
    }

    for (int j0 = 0; j0 < cnt; j0 += 32) {
        unsigned pr = 0u;
        if (j0 + l < cnt)
            pr = __builtin_nontemporal_load(scw4 + start + j0 + l);
        const int m = min(32, cnt - j0);

        int j = 0;
        for (; j + 8 <= m; j += 8) {
            const unsigned p0 = __shfl(pr, j, 32),     p1 = __shfl(pr, j + 1, 32);
            const unsigned p2 = __shfl(pr, j + 2, 32), p3 = __shfl(pr, j + 3, 32);
            const unsigned p4 = __shfl(pr, j + 4, 32), p5 = __shfl(pr, j + 5, 32);
            const unsigned p6 = __shfl(pr, j + 6, 32), p7 = __shfl(pr, j + 7, 32);
            GATHER_FMA_H(p0); GATHER_FMA_H(p1); GATHER_FMA_H(p2); GATHER_FMA_H(p3);
            GATHER_FMA_H(p4); GATHER_FMA_H(p5); GATHER_FMA_H(p6); GATHER_FMA_H(p7);
        }
        for (; j < m; ++j) {
            const unsigned p = __shfl(pr, j, 32);
            GATHER_FMA_H(p);
        }
    }
#undef GATHER_FMA_H

    f32x4 o; o[0] = acc.x; o[1] = acc.y; o[2] = acc.z; o[3] = acc.w;
    __builtin_nontemporal_store(o, (f32x4*)(outh + (size_t)row * OUT_F + l * 4));
}

// --------------------------- fallback path ---------------------------
__global__ __launch_bounds__(256) void bias_init_kernel(
    float* __restrict__ out, const float* __restrict__ bias, int total4)
{
    const float4* b4 = (const float4*)bias;
    float4* o4 = (float4*)out;
    for (int i = blockIdx.x * blockDim.x + threadIdx.x; i < total4;
         i += gridDim.x * blockDim.x)
        o4[i] = b4[i & 63];
}

__global__ __launch_bounds__(256) void edge_scatter_kernel(
    const int* __restrict__ ei, const float* __restrict__ ew,
    const __half* __restrict__ supA, const __half* __restrict__ supB,
    float* __restrict__ out, int E)
{
    const int e = blockIdx.x * 4 + (threadIdx.x >> 6);
    if (e >= E) return;
    const int lane = threadIdx.x & 63;
    const int   row = ei[e];
    const int   col = ei[E + e];
    const float wgt = ew[e];
    const __half* src = (lane < 32) ? supA : supB;
    const int fl = (lane & 31) * 4;
    const uint2 v = *(const uint2*)(src + (size_t)col * HALF_F + fl);
    const float2 f0 = __half22float2(*(const __half2*)&v.x);
    const float2 f1 = __half22float2(*(const __half2*)&v.y);
    float* o = out + (size_t)row * OUT_F + (lane >> 5) * HALF_F + fl;
    unsafeAtomicAdd(o + 0, wgt * f0.x);
    unsafeAtomicAdd(o + 1, wgt * f0.y);
    unsafeAtomicAdd(o + 2, wgt * f1.x);
    unsafeAtomicAdd(o + 3, wgt * f1.y);
}

// ---------------------------------------------------------------------------
extern "C" void kernel_launch(void* const* d_in, const int* in_sizes, int n_in,
                              void* d_out, int out_size, void* d_ws, size_t ws_size,
                              hipStream_t stream)
{
    const float* x    = (const float*)d_in[0];
    const int*   ei   = (const int*)d_in[1];
    const float* ew   = (const float*)d_in[2];
    const float* w    = (const float*)d_in[3];
    const float* bias = (const float*)d_in[4];
    float* out = (float*)d_out;

    const int M = in_sizes[0] / IN_F;   // 100000
    const int E = in_sizes[2];          // 3,200,000
    const int nbins = (M + RPB - 1) >> RPB_SHIFT;        // 196
    const int T     = (E + TILE_E - 1) / TILE_E;         // 782

    // workspace layout
    char* p = (char*)d_ws;
    const size_t suph_b   = (((size_t)M * HALF_F * sizeof(__half)) + 255) & ~255ull;
    const size_t counts_b = ((size_t)M * 4 + 255) & ~255ull;
    const size_t btot_b   = NBINS_MAX * 4;
    const size_t cstart_b = counts_b;
    const size_t bstart_b = NBINS_MAX * 4;
    const size_t thist_b  = (((size_t)T * NBINS_MAX * 4) + 255) & ~255ull;
    const size_t scw4_b   = ((size_t)E * 4 + 255) & ~255ull;
    const size_t tscw_b   = ((size_t)E * 8 + 255) & ~255ull;
    const size_t wt_b     = (size_t)IN_F * OUT_F * sizeof(short);
    const size_t need     = 2 * suph_b + counts_b + btot_b + cstart_b
                          + bstart_b + thist_b + scw4_b + tscw_b + wt_b;

    __half*   supA    = (__half*)p;            p += suph_b;
    __half*   supB    = (__half*)p;            p += suph_b;
    int*      counts  = (int*)p;               p += counts_b;
    int*      btot    = (int*)p;               p += btot_b;
    int*      cstart  = (int*)p;               p += cstart_b;
    int*      bstart  = (int*)p;               p += bstart_b;
    int*      thist   = (int*)p;               p += thist_b;
    unsigned* scw4    = (unsigned*)p;          p += scw4_b;
    ull*      tscw    = (ull*)p;               p += tscw_b;
    short*    wtb     = (short*)p;

    // 1) wt = bf16(w^T); supA/B = fp16(x @ W) via LDS-staged MFMA
    convert_wt_kernel<<<(IN_F * OUT_F) / 256, 256, 0, stream>>>(w, wtb);
    mfma_gemm_kernel<<<(M + 31) / 32, 256, 0, stream>>>(x, wtb, supA, supB, M);

    if (ws_size >= need) {
        // 2) CSR build: all bookkeeping in LDS, zero global atomics
        a1a_hist_kernel<<<T, 256, 0, stream>>>(ei, thist, E);
        tile_scan_kernel<<<nbins, 256, 0, stream>>>(thist, btot, T);
        bin_scan_kernel<<<1, NBINS_MAX, 0, stream>>>(btot, bstart, nbins);
        a1b_scatter_kernel<<<T, 256, 0, stream>>>(ei, ew, bstart, thist, tscw, E);
        a2_sort_kernel<<<nbins, 512, 0, stream>>>(
            tscw, bstart, btot, counts, cstart, scw4, M);
        // 3) pull, two feature-half passes
        const int pblocks = ((M + 1) / 2 + 3) / 4;
        pull_half_kernel<<<pblocks, 256, 0, stream>>>(
            counts, cstart, scw4, supA, bias, out, M);
        pull_half_kernel<<<pblocks, 256, 0, stream>>>(
            counts, cstart, scw4, supB, bias + HALF_F, out + HALF_F, M);
    } else {
        const int total4 = M * OUT_F / 4;
        bias_init_kernel<<<2048, 256, 0, stream>>>(out, bias, total4);
        edge_scatter_kernel<<<(E + 3) / 4, 256, 0, stream>>>(ei, ew, supA, supB, out, E);
    }
}

// Round 14
// 405.338 us; speedup vs baseline: 1.4459x; 1.0075x over previous
//
#include <hip/hip_runtime.h>
#include <hip/hip_fp16.h>
#include <hip/hip_cooperative_groups.h>

namespace cg = cooperative_groups;

#define IN_F 256
#define OUT_F 256
#define HALF_F 128
#define RPB_SHIFT 9          // 512 rows per bin
#define RPB (1 << RPB_SHIFT)
#define NBINS_MAX 256
#define TILE_E 4096
#define XS_PAD 40
#define SHARD_SHIFT 14       // shard = col >> 14 (8 shards x 3.2 MB sup-half)
#define NKEY (RPB * 8)       // 4096 keys per bin: (rowLo<<3)|shard
#define PULL_BLOCKS 1024     // x 256 thr, needs 4 blocks/CU co-resident
#define SLOTS (PULL_BLOCKS * 8)  // half-wave row slots per iteration (8192)
#define MAX_IT 13            // ceil(100000 / 8192)

using bf16x8 = __attribute__((ext_vector_type(8))) short;
using bf16x4 = __attribute__((ext_vector_type(4))) short;
using f32x4  = __attribute__((ext_vector_type(4))) float;
using ull    = unsigned long long;

__device__ inline short bf16rne(float f) {
    unsigned u = __float_as_uint(f);
    u = u + 0x7FFFu + ((u >> 16) & 1u);
    return (short)(u >> 16);
}
__device__ inline unsigned pack_half2(float a, float b) {
    __half2 h = __floats2half2_rn(a, b);
    return *reinterpret_cast<unsigned*>(&h);
}

// ---------------------------------------------------------------------------
// wt[n][k] = bf16(w[k][n])
// ---------------------------------------------------------------------------
__global__ __launch_bounds__(256) void convert_wt_kernel(
    const float* __restrict__ w, short* __restrict__ wt)
{
    const int idx = blockIdx.x * blockDim.x + threadIdx.x;
    const int c = idx >> 8, k = idx & 255;
    wt[(size_t)c * IN_F + k] = bf16rne(w[(size_t)k * OUT_F + c]);
}

// ---------------------------------------------------------------------------
// MFMA GEMM, LDS-staged + double-buffered, BM=32 (R8/R10-verified)
// ---------------------------------------------------------------------------
__global__ __launch_bounds__(256) void mfma_gemm_kernel(
    const float* __restrict__ x, const short* __restrict__ wt,
    __half* __restrict__ supA, __half* __restrict__ supB, int M)
{
    __shared__ short xs[2][32][XS_PAD];

    const int t    = threadIdx.x;
    const int lane = t & 63;
    const int wid  = t >> 6;
    const int l15  = lane & 15;
    const int l4   = lane >> 4;
    const int rowbase = blockIdx.x * 32;
    const int cbase   = wid * 64;

    const int srow = t >> 3;
    const int sks  = (t & 7) * 4;
    int grow = rowbase + srow; if (grow > M - 1) grow = M - 1;
    const float* xsrc = x + (size_t)grow * IN_F + sks;

    f32x4 acc[2][4];
#pragma unroll
    for (int rt = 0; rt < 2; ++rt)
#pragma unroll
        for (int ct = 0; ct < 4; ++ct)
            acc[rt][ct] = (f32x4){0.f, 0.f, 0.f, 0.f};

    const short* wp[4];
#pragma unroll
    for (int ct = 0; ct < 4; ++ct)
        wp[ct] = wt + (size_t)(cbase + ct * 16 + l15) * IN_F + l4 * 8;

    {
        const float4 f = *(const float4*)xsrc;
        bf16x4 v;
        v[0] = bf16rne(f.x); v[1] = bf16rne(f.y);
        v[2] = bf16rne(f.z); v[3] = bf16rne(f.w);
        *(bf16x4*)&xs[0][srow][sks] = v;
    }
    __syncthreads();

#pragma unroll
    for (int k0 = 0; k0 < 8; ++k0) {
        const int cur = k0 & 1;

        float4 nf;
        if (k0 < 7) nf = *(const float4*)(xsrc + (k0 + 1) * 32);

        bf16x8 b[4];
#pragma unroll
        for (int ct = 0; ct < 4; ++ct)
            b[ct] = *(const bf16x8*)(wp[ct] + k0 * 32);

        bf16x8 a[2];
#pragma unroll
        for (int rt = 0; rt < 2; ++rt)
            a[rt] = *(const bf16x8*)&xs[cur][rt * 16 + l15][l4 * 8];

#pragma unroll
        for (int rt = 0; rt < 2; ++rt)
#pragma unroll
            for (int ct = 0; ct < 4; ++ct)
                acc[rt][ct] = __builtin_amdgcn_mfma_f32_16x16x32_bf16(
                    b[ct], a[rt], acc[rt][ct], 0, 0, 0);

        if (k0 < 7) {
            bf16x4 v;
            v[0] = bf16rne(nf.x); v[1] = bf16rne(nf.y);
            v[2] = bf16rne(nf.z); v[3] = bf16rne(nf.w);
            *(bf16x4*)&xs[cur ^ 1][srow][sks] = v;
        }
        __syncthreads();
    }

    __half* dst = (wid < 2) ? supA : supB;
    const int fbase = (wid & 1) * 64;
#pragma unroll
    for (int rt = 0; rt < 2; ++rt) {
        const int r = rowbase + rt * 16 + l15;
        if (r >= M) continue;
#pragma unroll
        for (int ct = 0; ct < 4; ++ct) {
            uint2 pk;
            pk.x = pack_half2(acc[rt][ct][0], acc[rt][ct][1]);
            pk.y = pack_half2(acc[rt][ct][2], acc[rt][ct][3]);
            *(uint2*)(dst + (size_t)r * HALF_F + fbase + ct * 16 + l4 * 4) = pk;
        }
    }
}

// ---------------------------------------------------------------------------
// a1a: per-tile bin histogram -> thist[t][b]   (LDS atomics only)
// ---------------------------------------------------------------------------
__global__ __launch_bounds__(256) void a1a_hist_kernel(
    const int* __restrict__ ei, int* __restrict__ thist, int E)
{
    __shared__ int hist[NBINS_MAX];
    const int tid = threadIdx.x;
    hist[tid] = 0;
    __syncthreads();
    const int base = blockIdx.x * TILE_E;
#pragma unroll
    for (int i = 0; i < TILE_E / 256; ++i) {
        const int e = base + i * 256 + tid;
        if (e < E)
            atomicAdd(&hist[__builtin_nontemporal_load(ei + e) >> RPB_SHIFT], 1);
    }
    __syncthreads();
    thist[(size_t)blockIdx.x * NBINS_MAX + tid] = hist[tid];
}

// per-bin exclusive scan over tiles, in place; emits btot[b]
__global__ __launch_bounds__(256) void tile_scan_kernel(
    int* __restrict__ thist, int* __restrict__ btot, int T)
{
    const int b   = blockIdx.x;
    const int tid = threadIdx.x;
    __shared__ int s[256];
    int carry = 0;
    for (int c0 = 0; c0 < T; c0 += 256) {
        const int t = c0 + tid;
        const int v = (t < T) ? thist[(size_t)t * NBINS_MAX + b] : 0;
        s[tid] = v;
        __syncthreads();
        for (int d = 1; d < 256; d <<= 1) {
            const int u = (tid >= d) ? s[tid - d] : 0;
            __syncthreads();
            s[tid] += u;
            __syncthreads();
        }
        const int total = s[255];
        if (t < T) thist[(size_t)t * NBINS_MAX + b] = carry + s[tid] - v;
        carry += total;
        __syncthreads();
    }
    if (tid == 0) btot[b] = carry;
}

// exclusive scan of bin totals (1 block); writes pstart sentinel = E_total
__global__ __launch_bounds__(NBINS_MAX) void bin_scan_kernel(
    const int* __restrict__ btot, int* __restrict__ bstart,
    int* __restrict__ pstart, int nbins)
{
    __shared__ int s[NBINS_MAX];
    const int tid = threadIdx.x;
    const int v = (tid < nbins) ? btot[tid] : 0;
    s[tid] = v;
    __syncthreads();
    for (int d = 1; d < NBINS_MAX; d <<= 1) {
        const int u = (tid >= d) ? s[tid - d] : 0;
        __syncthreads();
        s[tid] += u;
        __syncthreads();
    }
    bstart[tid] = s[tid] - v;
    if (tid == 0) pstart[(size_t)nbins * NKEY] = s[NBINS_MAX - 1];
}

// ---------------------------------------------------------------------------
// a1b: deterministic binned scatter. Entry = (w:32 | col:17 | rowLo:9)
// ---------------------------------------------------------------------------
__global__ __launch_bounds__(256) void a1b_scatter_kernel(
    const int* __restrict__ ei, const float* __restrict__ ew,
    const int* __restrict__ bstart, const int* __restrict__ thist,
    ull* __restrict__ tscw, int E)
{
    __shared__ int hist[NBINS_MAX];
    __shared__ int rbase[NBINS_MAX];
    const int tid = threadIdx.x;
    hist[tid]  = 0;
    rbase[tid] = bstart[tid] + thist[(size_t)blockIdx.x * NBINS_MAX + tid];
    __syncthreads();
    const int base = blockIdx.x * TILE_E;
#pragma unroll
    for (int i = 0; i < TILE_E / 256; ++i) {
        const int e = base + i * 256 + tid;
        if (e < E) {
            const int      row = __builtin_nontemporal_load(ei + e);
            const int      col = __builtin_nontemporal_load(ei + E + e);
            const unsigned wb  = __builtin_nontemporal_load((const unsigned*)ew + e);
            const int b   = row >> RPB_SHIFT;
            const int rnk = atomicAdd(&hist[b], 1);
            tscw[rbase[b] + rnk] = ((ull)wb << 32) |
                                   ((unsigned)col << RPB_SHIFT) |
                                   (unsigned)(row & (RPB - 1));
        }
    }
}

// ---------------------------------------------------------------------------
// a2: in-bin LDS counting sort by key = (rowLo:9 | shard:3), 512 thr x 8 keys.
// Emits key-sorted 4B entries (w15|col17) and pstart[gkey]. Zero global atomics.
// ---------------------------------------------------------------------------
__global__ __launch_bounds__(512) void a2_sort_kernel(
    const ull* __restrict__ tscw, const int* __restrict__ bstart,
    const int* __restrict__ btot, int* __restrict__ pstart,
    unsigned* __restrict__ scw4)
{
    const int b   = blockIdx.x;
    const int tid = threadIdx.x;
    const int n   = btot[b];
    const int s0  = bstart[b];

    __shared__ int h[NKEY];
    __shared__ int s[512];

#pragma unroll
    for (int k = 0; k < NKEY / 512; ++k) h[tid + k * 512] = 0;
    __syncthreads();

    for (int i = tid; i < n; i += 512) {
        const ull en = __builtin_nontemporal_load(tscw + s0 + i);
        const int key = ((int)(en & (RPB - 1)) << 3) |
                        (int)((en >> (RPB_SHIFT + SHARD_SHIFT)) & 7u);
        atomicAdd(&h[key], 1);
    }
    __syncthreads();

    int loc[8];
    int run = 0;
#pragma unroll
    for (int k = 0; k < 8; ++k) { loc[k] = h[tid * 8 + k]; run += loc[k]; }
    s[tid] = run;
    __syncthreads();
    for (int d = 1; d < 512; d <<= 1) {
        const int u = (tid >= d) ? s[tid - d] : 0;
        __syncthreads();
        s[tid] += u;
        __syncthreads();
    }
    int accum = s[tid] - run;
    const size_t g0 = (size_t)b * NKEY + (size_t)tid * 8;
#pragma unroll
    for (int k = 0; k < 8; ++k) {
        pstart[g0 + k] = s0 + accum;
        loc[k] = s0 + accum;
        accum += h[tid * 8 + k];
    }
    __syncthreads();
#pragma unroll
    for (int k = 0; k < 8; ++k) h[tid * 8 + k] = loc[k];
    __syncthreads();

    for (int i = tid; i < n; i += 512) {
        const ull en = __builtin_nontemporal_load(tscw + s0 + i);
        const int key = ((int)(en & (RPB - 1)) << 3) |
                        (int)((en >> (RPB_SHIFT + SHARD_SHIFT)) & 7u);
        const unsigned col = (unsigned)((en >> RPB_SHIFT) & 0x1FFFFu);
        const float wf = __uint_as_float((unsigned)(en >> 32));
        const unsigned w15 = (unsigned)(wf * 32767.0f + 0.5f);
        const int pos = atomicAdd(&h[key], 1);
        scw4[pos] = (w15 << 17) | col;
    }
}

// ---------------------------------------------------------------------------
// Cooperative shard-phased pull (logic identical to R11).
// ---------------------------------------------------------------------------
__global__ __launch_bounds__(256, 4) void pull_coop_kernel(
    const int* __restrict__ pstart, const unsigned* __restrict__ scw4,
    const __half* __restrict__ supA, const __half* __restrict__ supB,
    const float* __restrict__ bias, float* __restrict__ out, int M)
{
    cg::grid_group grid = cg::this_grid();
    const int gw2 = (blockIdx.x * 256 + threadIdx.x) >> 5;   // 0..8191
    const int l   = threadIdx.x & 31;

#pragma unroll
    for (int half = 0; half < 2; ++half) {
        const __half* suph = half ? supB : supA;
        const float4 bv = *(const float4*)(bias + half * HALF_F + l * 4);

        float4 acc[MAX_IT];
#pragma unroll
        for (int it = 0; it < MAX_IT; ++it) acc[it] = bv;

        for (int sh = 0; sh < 8; ++sh) {
#pragma unroll
            for (int it = 0; it < MAX_IT; ++it) {
                const int row = it * SLOTS + gw2;
                if (row < M) {
                    const int st = pstart[(size_t)row * 8 + sh];
                    const int en = pstart[(size_t)row * 8 + sh + 1];
                    for (int j0 = st; j0 < en; j0 += 32) {
                        unsigned pr = 0u;
                        if (j0 + l < en) pr = scw4[j0 + l];
                        const int m = min(32, en - j0);
                        for (int j = 0; j < m; ++j) {
                            const unsigned pe = __shfl(pr, j, 32);
                            const int   c  = (int)(pe & 0x1FFFFu);
                            const float wj = (float)(pe >> 17) * (1.0f / 32767.0f);
                            const uint2 v = *(const uint2*)(suph + (size_t)c * HALF_F + l * 4);
                            const float2 f0 = __half22float2(*(const __half2*)&v.x);
                            const float2 f1 = __half22float2(*(const __half2*)&v.y);
                            acc[it].x = fmaf(wj, f0.x, acc[it].x);
                            acc[it].y = fmaf(wj, f0.y, acc[it].y);
                            acc[it].z = fmaf(wj, f1.x, acc[it].z);
                            acc[it].w = fmaf(wj, f1.y, acc[it].w);
                        }
                    }
                }
            }
            grid.sync();
        }

#pragma unroll
        for (int it = 0; it < MAX_IT; ++it) {
            const int row = it * SLOTS + gw2;
            if (row < M) {
                f32x4 o;
                o[0] = acc[it].x; o[1] = acc[it].y;
                o[2] = acc[it].z; o[3] = acc[it].w;
                __builtin_nontemporal_store(
                    o, (f32x4*)(out + (size_t)row * OUT_F + half * HALF_F + l * 4));
            }
        }
    }
}

// ---------------------------------------------------------------------------
// Fallback pull (R10-proven): wave = 2 rows x 32 lanes; start/cnt from pstart.
// start = pstart[row*8]; end = pstart[(row+1)*8] (contiguous keys + sentinel).
// ---------------------------------------------------------------------------
__global__ __launch_bounds__(256) void pull_half_kernel(
    const int* __restrict__ pstart, const unsigned* __restrict__ scw4,
    const __half* __restrict__ suph, const float* __restrict__ biash,
    float* __restrict__ outh, int M)
{
    const int wv  = blockIdx.x * 4 + (threadIdx.x >> 6);
    const int row = wv * 2 + ((threadIdx.x >> 5) & 1);
    if (row >= M) return;
    const int l = threadIdx.x & 31;

    const int start = pstart[(size_t)row * 8];
    const int cnt   = pstart[(size_t)row * 8 + 8] - start;

    float4 acc = *(const float4*)(biash + l * 4);

#define GATHER_FMA_H(pe)                                                      \
    {                                                                         \
        const int   c  = (int)((pe) & 0x1FFFFu);                              \
        const float wj = (float)((pe) >> 17) * (1.0f / 32767.0f);             \
        const uint2 v = *(const uint2*)(suph + (size_t)c * HALF_F + l * 4);   \
        const float2 f0 = __half22float2(*(const __half2*)&v.x);              \
        const float2 f1 = __half22float2(*(const __half2*)&v.y);              \
        acc.x = fmaf(wj, f0.x, acc.x); acc.y = fmaf(wj, f0.y, acc.y);         \
        acc.z = fmaf(wj, f1.x, acc.z); acc.w = fmaf(wj, f1.y, acc.w);         \
    }

    for (int j0 = 0; j0 < cnt; j0 += 32) {
        unsigned pr = 0u;
        if (j0 + l < cnt)
            pr = __builtin_nontemporal_load(scw4 + start + j0 + l);
        const int m = min(32, cnt - j0);

        int j = 0;
        for (; j + 8 <= m; j += 8) {
            const unsigned p0 = __shfl(pr, j, 32),     p1 = __shfl(pr, j + 1, 32);
            const unsigned p2 = __shfl(pr, j + 2, 32), p3 = __shfl(pr, j + 3, 32);
            const unsigned p4 = __shfl(pr, j + 4, 32), p5 = __shfl(pr, j + 5, 32);
            const unsigned p6 = __shfl(pr, j + 6, 32), p7 = __shfl(pr, j + 7, 32);
            GATHER_FMA_H(p0); GATHER_FMA_H(p1); GATHER_FMA_H(p2); GATHER_FMA_H(p3);
            GATHER_FMA_H(p4); GATHER_FMA_H(p5); GATHER_FMA_H(p6); GATHER_FMA_H(p7);
        }
        for (; j < m; ++j) {
            const unsigned p = __shfl(pr, j, 32);
            GATHER_FMA_H(p);
        }
    }
#undef GATHER_FMA_H

    f32x4 o; o[0] = acc.x; o[1] = acc.y; o[2] = acc.z; o[3] = acc.w;
    __builtin_nontemporal_store(o, (f32x4*)(outh + (size_t)row * OUT_F + l * 4));
}

// --------------------------- ws-too-small fallback ---------------------------
__global__ __launch_bounds__(256) void bias_init_kernel(
    float* __restrict__ out, const float* __restrict__ bias, int total4)
{
    const float4* b4 = (const float4*)bias;
    float4* o4 = (float4*)out;
    for (int i = blockIdx.x * blockDim.x + threadIdx.x; i < total4;
         i += gridDim.x * blockDim.x)
        o4[i] = b4[i & 63];
}

__global__ __launch_bounds__(256) void edge_scatter_kernel(
    const int* __restrict__ ei, const float* __restrict__ ew,
    const __half* __restrict__ supA, const __half* __restrict__ supB,
    float* __restrict__ out, int E)
{
    const int e = blockIdx.x * 4 + (threadIdx.x >> 6);
    if (e >= E) return;
    const int lane = threadIdx.x & 63;
    const int   row = ei[e];
    const int   col = ei[E + e];
    const float wgt = ew[e];
    const __half* src = (lane < 32) ? supA : supB;
    const int fl = (lane & 31) * 4;
    const uint2 v = *(const uint2*)(src + (size_t)col * HALF_F + fl);
    const float2 f0 = __half22float2(*(const __half2*)&v.x);
    const float2 f1 = __half22float2(*(const __half2*)&v.y);
    float* o = out + (size_t)row * OUT_F + (lane >> 5) * HALF_F + fl;
    unsafeAtomicAdd(o + 0, wgt * f0.x);
    unsafeAtomicAdd(o + 1, wgt * f0.y);
    unsafeAtomicAdd(o + 2, wgt * f1.x);
    unsafeAtomicAdd(o + 3, wgt * f1.y);
}

// ---------------------------------------------------------------------------
extern "C" void kernel_launch(void* const* d_in, const int* in_sizes, int n_in,
                              void* d_out, int out_size, void* d_ws, size_t ws_size,
                              hipStream_t stream)
{
    const float* x    = (const float*)d_in[0];
    const int*   ei   = (const int*)d_in[1];
    const float* ew   = (const float*)d_in[2];
    const float* w    = (const float*)d_in[3];
    const float* bias = (const float*)d_in[4];
    float* out = (float*)d_out;

    const int M = in_sizes[0] / IN_F;   // 100000
    const int E = in_sizes[2];          // 3,200,000
    const int nbins = (M + RPB - 1) >> RPB_SHIFT;        // 196
    const int T     = (E + TILE_E - 1) / TILE_E;         // 782

    // workspace layout
    char* p = (char*)d_ws;
    const size_t suph_b   = (((size_t)M * HALF_F * sizeof(__half)) + 255) & ~255ull;
    const size_t btot_b   = NBINS_MAX * 4;
    const size_t bstart_b = NBINS_MAX * 4;
    const size_t thist_b  = (((size_t)T * NBINS_MAX * 4) + 255) & ~255ull;
    const size_t pstart_b = (((size_t)nbins * NKEY + 256) * 4 + 255) & ~255ull;
    const size_t scw4_b   = ((size_t)E * 4 + 255) & ~255ull;
    const size_t tscw_b   = ((size_t)E * 8 + 255) & ~255ull;
    const size_t wt_b     = (size_t)IN_F * OUT_F * sizeof(short);
    const size_t need     = 2 * suph_b + btot_b + bstart_b + thist_b
                          + pstart_b + scw4_b + tscw_b + wt_b;

    __half*   supA    = (__half*)p;            p += suph_b;
    __half*   supB    = (__half*)p;            p += suph_b;
    int*      btot    = (int*)p;               p += btot_b;
    int*      bstart  = (int*)p;               p += bstart_b;
    int*      thist   = (int*)p;               p += thist_b;
    int*      pstart  = (int*)p;               p += pstart_b;
    unsigned* scw4    = (unsigned*)p;          p += scw4_b;
    ull*      tscw    = (ull*)p;               p += tscw_b;
    short*    wtb     = (short*)p;

    // 1) wt = bf16(w^T); supA/B = fp16(x @ W) via LDS-staged MFMA
    convert_wt_kernel<<<(IN_F * OUT_F) / 256, 256, 0, stream>>>(w, wtb);
    mfma_gemm_kernel<<<(M + 31) / 32, 256, 0, stream>>>(x, wtb, supA, supB, M);

    if (ws_size >= need) {
        // 2) CSR build: all bookkeeping in LDS, zero global atomics
        a1a_hist_kernel<<<T, 256, 0, stream>>>(ei, thist, E);
        tile_scan_kernel<<<nbins, 256, 0, stream>>>(thist, btot, T);
        bin_scan_kernel<<<1, NBINS_MAX, 0, stream>>>(btot, bstart, pstart, nbins);
        a1b_scatter_kernel<<<T, 256, 0, stream>>>(ei, ew, bstart, thist, tscw, E);
        a2_sort_kernel<<<nbins, 512, 0, stream>>>(tscw, bstart, btot, pstart, scw4);

        // 3) pull: cooperative shard-phased if the HW will actually run it;
        //    otherwise the R10-proven two-pass pull. All checks are host-side
        //    queries (capture-safe) + launch error code.
        bool coop_done = false;
        const bool rows_fit = ((M + SLOTS - 1) / SLOTS) <= MAX_IT;
        if (rows_fit) {
            int dev = 0;
            (void)hipGetDevice(&dev);
            int coopAttr = 0, numCU = 0, maxB = 0;
            (void)hipDeviceGetAttribute(&coopAttr, hipDeviceAttributeCooperativeLaunch, dev);
            (void)hipDeviceGetAttribute(&numCU, hipDeviceAttributeMultiprocessorCount, dev);
            hipError_t occ = hipOccupancyMaxActiveBlocksPerMultiprocessor(
                &maxB, pull_coop_kernel, 256, 0);
            if (coopAttr && occ == hipSuccess && (long long)maxB * numCU >= PULL_BLOCKS) {
                void* kargs[] = {(void*)&pstart, (void*)&scw4, (void*)&supA,
                                 (void*)&supB, (void*)&bias, (void*)&out, (void*)&M};
                hipError_t lerr = hipLaunchCooperativeKernel(
                    (void*)pull_coop_kernel, dim3(PULL_BLOCKS), dim3(256),
                    kargs, 0, stream);
                coop_done = (lerr == hipSuccess);
            }
        }
        if (!coop_done) {
            const int pblocks = ((M + 1) / 2 + 3) / 4;
            pull_half_kernel<<<pblocks, 256, 0, stream>>>(
                pstart, scw4, supA, bias, out, M);
            pull_half_kernel<<<pblocks, 256, 0, stream>>>(
                pstart, scw4, supB, bias + HALF_F, out + HALF_F, M);
        }
    } else {
        const int total4 = M * OUT_F / 4;
        bias_init_kernel<<<2048, 256, 0, stream>>>(out, bias, total4);
        edge_scatter_kernel<<<(E + 3) / 4, 256, 0, stream>>>(ei, ew, supA, supB, out, E);
    }
}

// Round 15
// 404.263 us; speedup vs baseline: 1.4498x; 1.0027x over previous
//
#include <hip/hip_runtime.h>
#include <hip/hip_fp16.h>

#define IN_F 256
#define OUT_F 256
#define HALF_F 128
#define RPB_SHIFT 9          // 512 rows per bin
#define RPB (1 << RPB_SHIFT)
#define NBINS_MAX 256
#define TILE_E 4096
#define XS_PAD 40            // LDS row stride in bf16 (80 B; 16B-aligned, bank-spread)

using bf16x8 = __attribute__((ext_vector_type(8))) short;
using bf16x4 = __attribute__((ext_vector_type(4))) short;
using f32x4  = __attribute__((ext_vector_type(4))) float;
using ull    = unsigned long long;

__device__ inline short bf16rne(float f) {
    unsigned u = __float_as_uint(f);
    u = u + 0x7FFFu + ((u >> 16) & 1u);
    return (short)(u >> 16);
}
__device__ inline unsigned pack_half2(float a, float b) {
    __half2 h = __floats2half2_rn(a, b);
    return *reinterpret_cast<unsigned*>(&h);
}

// ---------------------------------------------------------------------------
// wt[n][k] = bf16(w[k][n])
// ---------------------------------------------------------------------------
__global__ __launch_bounds__(256) void convert_wt_kernel(
    const float* __restrict__ w, short* __restrict__ wt)
{
    const int idx = blockIdx.x * blockDim.x + threadIdx.x;
    const int c = idx >> 8, k = idx & 255;
    wt[(size_t)c * IN_F + k] = bf16rne(w[(size_t)k * OUT_F + c]);
}

// ---------------------------------------------------------------------------
// MFMA GEMM, LDS-staged + double-buffered, BM=32 (R8/R10-verified)
// ---------------------------------------------------------------------------
__global__ __launch_bounds__(256) void mfma_gemm_kernel(
    const float* __restrict__ x, const short* __restrict__ wt,
    __half* __restrict__ supA, __half* __restrict__ supB, int M)
{
    __shared__ short xs[2][32][XS_PAD];

    const int t    = threadIdx.x;
    const int lane = t & 63;
    const int wid  = t >> 6;
    const int l15  = lane & 15;
    const int l4   = lane >> 4;
    const int rowbase = blockIdx.x * 32;
    const int cbase   = wid * 64;

    const int srow = t >> 3;
    const int sks  = (t & 7) * 4;
    int grow = rowbase + srow; if (grow > M - 1) grow = M - 1;
    const float* xsrc = x + (size_t)grow * IN_F + sks;

    f32x4 acc[2][4];
#pragma unroll
    for (int rt = 0; rt < 2; ++rt)
#pragma unroll
        for (int ct = 0; ct < 4; ++ct)
            acc[rt][ct] = (f32x4){0.f, 0.f, 0.f, 0.f};

    const short* wp[4];
#pragma unroll
    for (int ct = 0; ct < 4; ++ct)
        wp[ct] = wt + (size_t)(cbase + ct * 16 + l15) * IN_F + l4 * 8;

    {
        const float4 f = *(const float4*)xsrc;
        bf16x4 v;
        v[0] = bf16rne(f.x); v[1] = bf16rne(f.y);
        v[2] = bf16rne(f.z); v[3] = bf16rne(f.w);
        *(bf16x4*)&xs[0][srow][sks] = v;
    }
    __syncthreads();

#pragma unroll
    for (int k0 = 0; k0 < 8; ++k0) {
        const int cur = k0 & 1;

        float4 nf;
        if (k0 < 7) nf = *(const float4*)(xsrc + (k0 + 1) * 32);

        bf16x8 b[4];
#pragma unroll
        for (int ct = 0; ct < 4; ++ct)
            b[ct] = *(const bf16x8*)(wp[ct] + k0 * 32);

        bf16x8 a[2];
#pragma unroll
        for (int rt = 0; rt < 2; ++rt)
            a[rt] = *(const bf16x8*)&xs[cur][rt * 16 + l15][l4 * 8];

#pragma unroll
        for (int rt = 0; rt < 2; ++rt)
#pragma unroll
            for (int ct = 0; ct < 4; ++ct)
                acc[rt][ct] = __builtin_amdgcn_mfma_f32_16x16x32_bf16(
                    b[ct], a[rt], acc[rt][ct], 0, 0, 0);

        if (k0 < 7) {
            bf16x4 v;
            v[0] = bf16rne(nf.x); v[1] = bf16rne(nf.y);
            v[2] = bf16rne(nf.z); v[3] = bf16rne(nf.w);
            *(bf16x4*)&xs[cur ^ 1][srow][sks] = v;
        }
        __syncthreads();
    }

    __half* dst = (wid < 2) ? supA : supB;
    const int fbase = (wid & 1) * 64;
#pragma unroll
    for (int rt = 0; rt < 2; ++rt) {
        const int r = rowbase + rt * 16 + l15;
        if (r >= M) continue;
#pragma unroll
        for (int ct = 0; ct < 4; ++ct) {
            uint2 pk;
            pk.x = pack_half2(acc[rt][ct][0], acc[rt][ct][1]);
            pk.y = pack_half2(acc[rt][ct][2], acc[rt][ct][3]);
            *(uint2*)(dst + (size_t)r * HALF_F + fbase + ct * 16 + l4 * 4) = pk;
        }
    }
}

// ---------------------------------------------------------------------------
// a1a: per-tile bin histogram -> thist[t][b]   (LDS atomics only)
// ---------------------------------------------------------------------------
__global__ __launch_bounds__(256) void a1a_hist_kernel(
    const int* __restrict__ ei, int* __restrict__ thist, int E)
{
    __shared__ int hist[NBINS_MAX];
    const int tid = threadIdx.x;
    hist[tid] = 0;
    __syncthreads();
    const int base = blockIdx.x * TILE_E;
#pragma unroll
    for (int i = 0; i < TILE_E / 256; ++i) {
        const int e = base + i * 256 + tid;
        if (e < E)
            atomicAdd(&hist[__builtin_nontemporal_load(ei + e) >> RPB_SHIFT], 1);
    }
    __syncthreads();
    thist[(size_t)blockIdx.x * NBINS_MAX + tid] = hist[tid];
}

// per-bin exclusive scan over tiles, in place; emits btot[b]
__global__ __launch_bounds__(256) void tile_scan_kernel(
    int* __restrict__ thist, int* __restrict__ btot, int T)
{
    const int b   = blockIdx.x;
    const int tid = threadIdx.x;
    __shared__ int s[256];
    int carry = 0;
    for (int c0 = 0; c0 < T; c0 += 256) {
        const int t = c0 + tid;
        const int v = (t < T) ? thist[(size_t)t * NBINS_MAX + b] : 0;
        s[tid] = v;
        __syncthreads();
        for (int d = 1; d < 256; d <<= 1) {
            const int u = (tid >= d) ? s[tid - d] : 0;
            __syncthreads();
            s[tid] += u;
            __syncthreads();
        }
        const int total = s[255];
        if (t < T) thist[(size_t)t * NBINS_MAX + b] = carry + s[tid] - v;
        carry += total;
        __syncthreads();
    }
    if (tid == 0) btot[b] = carry;
}

// exclusive scan of bin totals (1 block)
__global__ __launch_bounds__(NBINS_MAX) void bin_scan_kernel(
    const int* __restrict__ btot, int* __restrict__ bstart, int nbins)
{
    __shared__ int s[NBINS_MAX];
    const int tid = threadIdx.x;
    const int v = (tid < nbins) ? btot[tid] : 0;
    s[tid] = v;
    __syncthreads();
    for (int d = 1; d < NBINS_MAX; d <<= 1) {
        const int u = (tid >= d) ? s[tid - d] : 0;
        __syncthreads();
        s[tid] += u;
        __syncthreads();
    }
    bstart[tid] = s[tid] - v;
}

// ---------------------------------------------------------------------------
// a1b: deterministic binned scatter. Entry = (w:32 | col:17 | rowLo:9)
// ---------------------------------------------------------------------------
__global__ __launch_bounds__(256) void a1b_scatter_kernel(
    const int* __restrict__ ei, const float* __restrict__ ew,
    const int* __restrict__ bstart, const int* __restrict__ thist,
    ull* __restrict__ tscw, int E)
{
    __shared__ int hist[NBINS_MAX];
    __shared__ int rbase[NBINS_MAX];
    const int tid = threadIdx.x;
    hist[tid]  = 0;
    rbase[tid] = bstart[tid] + thist[(size_t)blockIdx.x * NBINS_MAX + tid];
    __syncthreads();
    const int base = blockIdx.x * TILE_E;
#pragma unroll
    for (int i = 0; i < TILE_E / 256; ++i) {
        const int e = base + i * 256 + tid;
        if (e < E) {
            const int      row = __builtin_nontemporal_load(ei + e);
            const int      col = __builtin_nontemporal_load(ei + E + e);
            const unsigned wb  = __builtin_nontemporal_load((const unsigned*)ew + e);
            const int b   = row >> RPB_SHIFT;
            const int rnk = atomicAdd(&hist[b], 1);
            tscw[rbase[b] + rnk] = ((ull)wb << 32) |
                                   ((unsigned)col << RPB_SHIFT) |
                                   (unsigned)(row & (RPB - 1));
        }
    }
}

// ---------------------------------------------------------------------------
// a2: in-bin LDS counting sort by rowLo (512 keys), 1024 threads/block
// (halves the strided data passes vs 512). Emits row-sorted 4B entries
// (w15|col17), counts[row], cursor[row]. Zero global atomics.
// ---------------------------------------------------------------------------
__global__ __launch_bounds__(1024) void a2_sort_kernel(
    const ull* __restrict__ tscw, const int* __restrict__ bstart,
    const int* __restrict__ btot, int* __restrict__ counts,
    int* __restrict__ cursor, unsigned* __restrict__ scw4, int M)
{
    const int b   = blockIdx.x;
    const int tid = threadIdx.x;
    const int n   = btot[b];
    const int s0  = bstart[b];

    __shared__ int hist[RPB];
    __shared__ int cur[RPB];
    __shared__ int s[RPB];

    if (tid < RPB) hist[tid] = 0;
    __syncthreads();

    for (int i = tid; i < n; i += 1024)
        atomicAdd(&hist[(int)(__builtin_nontemporal_load(tscw + s0 + i) & (RPB - 1))], 1);
    __syncthreads();

    // exclusive scan of 512 (Hillis-Steele; threads >= RPB just hit barriers)
    int own = 0;
    if (tid < RPB) { own = hist[tid]; s[tid] = own; }
    __syncthreads();
    for (int d = 1; d < RPB; d <<= 1) {
        int u = 0;
        if (tid < RPB && tid >= d) u = s[tid - d];
        __syncthreads();
        if (tid < RPB) s[tid] += u;
        __syncthreads();
    }

    if (tid < RPB) {
        const int excl = s[tid] - own;
        const int grow = (b << RPB_SHIFT) + tid;
        if (grow < M) { counts[grow] = own; cursor[grow] = s0 + excl; }
        cur[tid] = s0 + excl;
    }
    __syncthreads();

    for (int i = tid; i < n; i += 1024) {
        const ull en = __builtin_nontemporal_load(tscw + s0 + i);
        const int key = (int)(en & (RPB - 1));
        const unsigned col = (unsigned)((en >> RPB_SHIFT) & 0x1FFFFu);
        const float wf = __uint_as_float((unsigned)(en >> 32));
        const unsigned w15 = (unsigned)(wf * 32767.0f + 0.5f);
        const int pos = atomicAdd(&cur[key], 1);
        scw4[pos] = (w15 << 17) | col;
    }
}

// ---------------------------------------------------------------------------
// Pull, feature-half pass: wave = 2 rows x 32 lanes; 4 B entries; 8-wide ILP.
// (R10-proven; at its gather roofline per R8/R12 falsification attempts)
// ---------------------------------------------------------------------------
__global__ __launch_bounds__(256) void pull_half_kernel(
    const int* __restrict__ counts, const int* __restrict__ cur_start,
    const unsigned* __restrict__ scw4, const __half* __restrict__ suph,
    const float* __restrict__ biash, float* __restrict__ outh, int M)
{
    const int wv  = blockIdx.x * 4 + (threadIdx.x >> 6);
    const int row = wv * 2 + ((threadIdx.x >> 5) & 1);
    if (row >= M) return;
    const int l = threadIdx.x & 31;

    const int cnt   = counts[row];
    const int start = cur_start[row];

    float4 acc = *(const float4*)(biash + l * 4);

#define GATHER_FMA_H(pe)                                                      \
    {                                                                         \
        const int   c  = (int)((pe) & 0x1FFFFu);                              \
        const float wj = (float)((pe) >> 17) * (1.0f / 32767.0f);             \
        const uint2 v = *(const uint2*)(suph + (size_t)c * HALF_F + l * 4);   \
        const float2 f0 = __half22float2(*(const __half2*)&v.x);              \
        const float2 f1 = __half22float2(*(const __half2*)&v.y);              \
        acc.x = fmaf(wj, f0.x, acc.x); acc.y = fmaf(wj, f0.y, acc.y);         \
        acc.z = fmaf(wj, f1.x, acc.z); acc.w = fmaf(wj, f1.y, acc.w);         \
    }

    for (int j0 = 0; j0 < cnt; j0 += 32) {
        unsigned pr = 0u;
        if (j0 + l < cnt)
            pr = __builtin_nontemporal_load(scw4 + start + j0 + l);
        const int m = min(32, cnt - j0);

        int j = 0;
        for (; j + 8 <= m; j += 8) {
            const unsigned p0 = __shfl(pr, j, 32),     p1 = __shfl(pr, j + 1, 32);
            const unsigned p2 = __shfl(pr, j + 2, 32), p3 = __shfl(pr, j + 3, 32);
            const unsigned p4 = __shfl(pr, j + 4, 32), p5 = __shfl(pr, j + 5, 32);
            const unsigned p6 = __shfl(pr, j + 6, 32), p7 = __shfl(pr, j + 7, 32);
            GATHER_FMA_H(p0); GATHER_FMA_H(p1); GATHER_FMA_H(p2); GATHER_FMA_H(p3);
            GATHER_FMA_H(p4); GATHER_FMA_H(p5); GATHER_FMA_H(p6); GATHER_FMA_H(p7);
        }
        for (; j < m; ++j) {
            const unsigned p = __shfl(pr, j, 32);
            GATHER_FMA_H(p);
        }
    }
#undef GATHER_FMA_H

    f32x4 o; o[0] = acc.x; o[1] = acc.y; o[2] = acc.z; o[3] = acc.w;
    __builtin_nontemporal_store(o, (f32x4*)(outh + (size_t)row * OUT_F + l * 4));
}

// --------------------------- ws-too-small fallback ---------------------------
__global__ __launch_bounds__(256) void bias_init_kernel(
    float* __restrict__ out, const float* __restrict__ bias, int total4)
{
    const float4* b4 = (const float4*)bias;
    float4* o4 = (float4*)out;
    for (int i = blockIdx.x * blockDim.x + threadIdx.x; i < total4;
         i += gridDim.x * blockDim.x)
        o4[i] = b4[i & 63];
}

__global__ __launch_bounds__(256) void edge_scatter_kernel(
    const int* __restrict__ ei, const float* __restrict__ ew,
    const __half* __restrict__ supA, const __half* __restrict__ supB,
    float* __restrict__ out, int E)
{
    const int e = blockIdx.x * 4 + (threadIdx.x >> 6);
    if (e >= E) return;
    const int lane = threadIdx.x & 63;
    const int   row = ei[e];
    const int   col = ei[E + e];
    const float wgt = ew[e];
    const __half* src = (lane < 32) ? supA : supB;
    const int fl = (lane & 31) * 4;
    const uint2 v = *(const uint2*)(src + (size_t)col * HALF_F + fl);
    const float2 f0 = __half22float2(*(const __half2*)&v.x);
    const float2 f1 = __half22float2(*(const __half2*)&v.y);
    float* o = out + (size_t)row * OUT_F + (lane >> 5) * HALF_F + fl;
    unsafeAtomicAdd(o + 0, wgt * f0.x);
    unsafeAtomicAdd(o + 1, wgt * f0.y);
    unsafeAtomicAdd(o + 2, wgt * f1.x);
    unsafeAtomicAdd(o + 3, wgt * f1.y);
}

// ---------------------------------------------------------------------------
extern "C" void kernel_launch(void* const* d_in, const int* in_sizes, int n_in,
                              void* d_out, int out_size, void* d_ws, size_t ws_size,
                              hipStream_t stream)
{
    const float* x    = (const float*)d_in[0];
    const int*   ei   = (const int*)d_in[1];
    const float* ew   = (const float*)d_in[2];
    const float* w    = (const float*)d_in[3];
    const float* bias = (const float*)d_in[4];
    float* out = (float*)d_out;

    const int M = in_sizes[0] / IN_F;   // 100000
    const int E = in_sizes[2];          // 3,200,000
    const int nbins = (M + RPB - 1) >> RPB_SHIFT;        // 196
    const int T     = (E + TILE_E - 1) / TILE_E;         // 782

    // workspace layout
    char* p = (char*)d_ws;
    const size_t suph_b   = (((size_t)M * HALF_F * sizeof(__half)) + 255) & ~255ull;
    const size_t counts_b = ((size_t)M * 4 + 255) & ~255ull;
    const size_t btot_b   = NBINS_MAX * 4;
    const size_t cstart_b = counts_b;
    const size_t bstart_b = NBINS_MAX * 4;
    const size_t thist_b  = (((size_t)T * NBINS_MAX * 4) + 255) & ~255ull;
    const size_t scw4_b   = ((size_t)E * 4 + 255) & ~255ull;
    const size_t tscw_b   = ((size_t)E * 8 + 255) & ~255ull;
    const size_t wt_b     = (size_t)IN_F * OUT_F * sizeof(short);
    const size_t need     = 2 * suph_b + counts_b + btot_b + cstart_b
                          + bstart_b + thist_b + scw4_b + tscw_b + wt_b;

    __half*   supA    = (__half*)p;            p += suph_b;
    __half*   supB    = (__half*)p;            p += suph_b;
    int*      counts  = (int*)p;               p += counts_b;
    int*      btot    = (int*)p;               p += btot_b;
    int*      cstart  = (int*)p;               p += cstart_b;
    int*      bstart  = (int*)p;               p += bstart_b;
    int*      thist   = (int*)p;               p += thist_b;
    unsigned* scw4    = (unsigned*)p;          p += scw4_b;
    ull*      tscw    = (ull*)p;               p += tscw_b;
    short*    wtb     = (short*)p;

    // 1) wt = bf16(w^T); supA/B = fp16(x @ W) via LDS-staged MFMA
    convert_wt_kernel<<<(IN_F * OUT_F) / 256, 256, 0, stream>>>(w, wtb);
    mfma_gemm_kernel<<<(M + 31) / 32, 256, 0, stream>>>(x, wtb, supA, supB, M);

    if (ws_size >= need) {
        // 2) CSR build: all bookkeeping in LDS, zero global atomics
        a1a_hist_kernel<<<T, 256, 0, stream>>>(ei, thist, E);
        tile_scan_kernel<<<nbins, 256, 0, stream>>>(thist, btot, T);
        bin_scan_kernel<<<1, NBINS_MAX, 0, stream>>>(btot, bstart, nbins);
        a1b_scatter_kernel<<<T, 256, 0, stream>>>(ei, ew, bstart, thist, tscw, E);
        a2_sort_kernel<<<nbins, 1024, 0, stream>>>(
            tscw, bstart, btot, counts, cstart, scw4, M);
        // 3) pull, two feature-half passes
        const int pblocks = ((M + 1) / 2 + 3) / 4;
        pull_half_kernel<<<pblocks, 256, 0, stream>>>(
            counts, cstart, scw4, supA, bias, out, M);
        pull_half_kernel<<<pblocks, 256, 0, stream>>>(
            counts, cstart, scw4, supB, bias + HALF_F, out + HALF_F, M);
    } else {
        const int total4 = M * OUT_F / 4;
        bias_init_kernel<<<2048, 256, 0, stream>>>(out, bias, total4);
        edge_scatter_kernel<<<(E + 3) / 4, 256, 0, stream>>>(ei, ew, supA, supB, out, E);
    }
}

// Round 16
// 403.122 us; speedup vs baseline: 1.4539x; 1.0028x over previous
//
#include <hip/hip_runtime.h>
#include <hip/hip_fp16.h>

#define IN_F 256
#define OUT_F 256
#define HALF_F 128
#define RPB_SHIFT 8          // 256 rows per bin (R14: was 512 — occupancy)
#define RPB (1 << RPB_SHIFT)
#define NBINS_MAX 512        // ceil(100000/256)=391 <= 512
#define TILE_E 4096
#define XS_PAD 40            // LDS row stride in bf16 (80 B; 16B-aligned, bank-spread)

using bf16x8 = __attribute__((ext_vector_type(8))) short;
using bf16x4 = __attribute__((ext_vector_type(4))) short;
using f32x4  = __attribute__((ext_vector_type(4))) float;
using ull    = unsigned long long;

__device__ inline short bf16rne(float f) {
    unsigned u = __float_as_uint(f);
    u = u + 0x7FFFu + ((u >> 16) & 1u);
    return (short)(u >> 16);
}
__device__ inline unsigned pack_half2(float a, float b) {
    __half2 h = __floats2half2_rn(a, b);
    return *reinterpret_cast<unsigned*>(&h);
}

// ---------------------------------------------------------------------------
// wt[n][k] = bf16(w[k][n])
// ---------------------------------------------------------------------------
__global__ __launch_bounds__(256) void convert_wt_kernel(
    const float* __restrict__ w, short* __restrict__ wt)
{
    const int idx = blockIdx.x * blockDim.x + threadIdx.x;
    const int c = idx >> 8, k = idx & 255;
    wt[(size_t)c * IN_F + k] = bf16rne(w[(size_t)k * OUT_F + c]);
}

// ---------------------------------------------------------------------------
// MFMA GEMM, LDS-staged + double-buffered, BM=32 (R8/R10-verified, frozen)
// ---------------------------------------------------------------------------
__global__ __launch_bounds__(256) void mfma_gemm_kernel(
    const float* __restrict__ x, const short* __restrict__ wt,
    __half* __restrict__ supA, __half* __restrict__ supB, int M)
{
    __shared__ short xs[2][32][XS_PAD];

    const int t    = threadIdx.x;
    const int lane = t & 63;
    const int wid  = t >> 6;
    const int l15  = lane & 15;
    const int l4   = lane >> 4;
    const int rowbase = blockIdx.x * 32;
    const int cbase   = wid * 64;

    const int srow = t >> 3;
    const int sks  = (t & 7) * 4;
    int grow = rowbase + srow; if (grow > M - 1) grow = M - 1;
    const float* xsrc = x + (size_t)grow * IN_F + sks;

    f32x4 acc[2][4];
#pragma unroll
    for (int rt = 0; rt < 2; ++rt)
#pragma unroll
        for (int ct = 0; ct < 4; ++ct)
            acc[rt][ct] = (f32x4){0.f, 0.f, 0.f, 0.f};

    const short* wp[4];
#pragma unroll
    for (int ct = 0; ct < 4; ++ct)
        wp[ct] = wt + (size_t)(cbase + ct * 16 + l15) * IN_F + l4 * 8;

    {
        const float4 f = *(const float4*)xsrc;
        bf16x4 v;
        v[0] = bf16rne(f.x); v[1] = bf16rne(f.y);
        v[2] = bf16rne(f.z); v[3] = bf16rne(f.w);
        *(bf16x4*)&xs[0][srow][sks] = v;
    }
    __syncthreads();

#pragma unroll
    for (int k0 = 0; k0 < 8; ++k0) {
        const int cur = k0 & 1;

        float4 nf;
        if (k0 < 7) nf = *(const float4*)(xsrc + (k0 + 1) * 32);

        bf16x8 b[4];
#pragma unroll
        for (int ct = 0; ct < 4; ++ct)
            b[ct] = *(const bf16x8*)(wp[ct] + k0 * 32);

        bf16x8 a[2];
#pragma unroll
        for (int rt = 0; rt < 2; ++rt)
            a[rt] = *(const bf16x8*)&xs[cur][rt * 16 + l15][l4 * 8];

#pragma unroll
        for (int rt = 0; rt < 2; ++rt)
#pragma unroll
            for (int ct = 0; ct < 4; ++ct)
                acc[rt][ct] = __builtin_amdgcn_mfma_f32_16x16x32_bf16(
                    b[ct], a[rt], acc[rt][ct], 0, 0, 0);

        if (k0 < 7) {
            bf16x4 v;
            v[0] = bf16rne(nf.x); v[1] = bf16rne(nf.y);
            v[2] = bf16rne(nf.z); v[3] = bf16rne(nf.w);
            *(bf16x4*)&xs[cur ^ 1][srow][sks] = v;
        }
        __syncthreads();
    }

    __half* dst = (wid < 2) ? supA : supB;
    const int fbase = (wid & 1) * 64;
#pragma unroll
    for (int rt = 0; rt < 2; ++rt) {
        const int r = rowbase + rt * 16 + l15;
        if (r >= M) continue;
#pragma unroll
        for (int ct = 0; ct < 4; ++ct) {
            uint2 pk;
            pk.x = pack_half2(acc[rt][ct][0], acc[rt][ct][1]);
            pk.y = pack_half2(acc[rt][ct][2], acc[rt][ct][3]);
            *(uint2*)(dst + (size_t)r * HALF_F + fbase + ct * 16 + l4 * 4) = pk;
        }
    }
}

// ---------------------------------------------------------------------------
// a1a: per-tile bin histogram -> thist[t][b]   (512 bins, LDS atomics only)
// ---------------------------------------------------------------------------
__global__ __launch_bounds__(256) void a1a_hist_kernel(
    const int* __restrict__ ei, int* __restrict__ thist, int E)
{
    __shared__ int hist[NBINS_MAX];
    const int tid = threadIdx.x;
    hist[tid] = 0; hist[tid + 256] = 0;
    __syncthreads();
    const int base = blockIdx.x * TILE_E;
#pragma unroll
    for (int i = 0; i < TILE_E / 256; ++i) {
        const int e = base + i * 256 + tid;
        if (e < E)
            atomicAdd(&hist[__builtin_nontemporal_load(ei + e) >> RPB_SHIFT], 1);
    }
    __syncthreads();
    thist[(size_t)blockIdx.x * NBINS_MAX + tid]       = hist[tid];
    thist[(size_t)blockIdx.x * NBINS_MAX + tid + 256] = hist[tid + 256];
}

// per-bin exclusive scan over tiles, in place; emits btot[b]  (391 blocks)
__global__ __launch_bounds__(256) void tile_scan_kernel(
    int* __restrict__ thist, int* __restrict__ btot, int T)
{
    const int b   = blockIdx.x;
    const int tid = threadIdx.x;
    __shared__ int s[256];
    int carry = 0;
    for (int c0 = 0; c0 < T; c0 += 256) {
        const int t = c0 + tid;
        const int v = (t < T) ? thist[(size_t)t * NBINS_MAX + b] : 0;
        s[tid] = v;
        __syncthreads();
        for (int d = 1; d < 256; d <<= 1) {
            const int u = (tid >= d) ? s[tid - d] : 0;
            __syncthreads();
            s[tid] += u;
            __syncthreads();
        }
        const int total = s[255];
        if (t < T) thist[(size_t)t * NBINS_MAX + b] = carry + s[tid] - v;
        carry += total;
        __syncthreads();
    }
    if (tid == 0) btot[b] = carry;
}

// exclusive scan of bin totals (1 block, 512 threads)
__global__ __launch_bounds__(NBINS_MAX) void bin_scan_kernel(
    const int* __restrict__ btot, int* __restrict__ bstart, int nbins)
{
    __shared__ int s[NBINS_MAX];
    const int tid = threadIdx.x;
    const int v = (tid < nbins) ? btot[tid] : 0;
    s[tid] = v;
    __syncthreads();
    for (int d = 1; d < NBINS_MAX; d <<= 1) {
        const int u = (tid >= d) ? s[tid - d] : 0;
        __syncthreads();
        s[tid] += u;
        __syncthreads();
    }
    bstart[tid] = s[tid] - v;
}

// ---------------------------------------------------------------------------
// a1b: deterministic binned scatter. Entry = (w:32 | col:17 | rowLo:8)
// ---------------------------------------------------------------------------
__global__ __launch_bounds__(256) void a1b_scatter_kernel(
    const int* __restrict__ ei, const float* __restrict__ ew,
    const int* __restrict__ bstart, const int* __restrict__ thist,
    ull* __restrict__ tscw, int E)
{
    __shared__ int hist[NBINS_MAX];
    __shared__ int rbase[NBINS_MAX];
    const int tid = threadIdx.x;
    hist[tid] = 0; hist[tid + 256] = 0;
    rbase[tid]       = bstart[tid]       + thist[(size_t)blockIdx.x * NBINS_MAX + tid];
    rbase[tid + 256] = bstart[tid + 256] + thist[(size_t)blockIdx.x * NBINS_MAX + tid + 256];
    __syncthreads();
    const int base = blockIdx.x * TILE_E;
#pragma unroll
    for (int i = 0; i < TILE_E / 256; ++i) {
        const int e = base + i * 256 + tid;
        if (e < E) {
            const int      row = __builtin_nontemporal_load(ei + e);
            const int      col = __builtin_nontemporal_load(ei + E + e);
            const unsigned wb  = __builtin_nontemporal_load((const unsigned*)ew + e);
            const int b   = row >> RPB_SHIFT;
            const int rnk = atomicAdd(&hist[b], 1);
            tscw[rbase[b] + rnk] = ((ull)wb << 32) |
                                   ((unsigned)col << RPB_SHIFT) |
                                   (unsigned)(row & (RPB - 1));
        }
    }
}

// ---------------------------------------------------------------------------
// a2: in-bin LDS counting sort by rowLo (256 keys), 1024 thr, 391 blocks.
// Emits row-sorted 4B entries (w15|col17), counts[row], cursor[row].
// Zero global atomics.
// ---------------------------------------------------------------------------
__global__ __launch_bounds__(1024) void a2_sort_kernel(
    const ull* __restrict__ tscw, const int* __restrict__ bstart,
    const int* __restrict__ btot, int* __restrict__ counts,
    int* __restrict__ cursor, unsigned* __restrict__ scw4, int M)
{
    const int b   = blockIdx.x;
    const int tid = threadIdx.x;
    const int n   = btot[b];
    const int s0  = bstart[b];

    __shared__ int hist[RPB];
    __shared__ int cur[RPB];
    __shared__ int s[RPB];

    if (tid < RPB) hist[tid] = 0;
    __syncthreads();

    for (int i = tid; i < n; i += 1024)
        atomicAdd(&hist[(int)(__builtin_nontemporal_load(tscw + s0 + i) & (RPB - 1))], 1);
    __syncthreads();

    // exclusive scan of 256 (Hillis-Steele; threads >= RPB just hit barriers)
    int own = 0;
    if (tid < RPB) { own = hist[tid]; s[tid] = own; }
    __syncthreads();
    for (int d = 1; d < RPB; d <<= 1) {
        int u = 0;
        if (tid < RPB && tid >= d) u = s[tid - d];
        __syncthreads();
        if (tid < RPB) s[tid] += u;
        __syncthreads();
    }

    if (tid < RPB) {
        const int excl = s[tid] - own;
        const int grow = (b << RPB_SHIFT) + tid;
        if (grow < M) { counts[grow] = own; cursor[grow] = s0 + excl; }
        cur[tid] = s0 + excl;
    }
    __syncthreads();

    for (int i = tid; i < n; i += 1024) {
        const ull en = __builtin_nontemporal_load(tscw + s0 + i);
        const int key = (int)(en & (RPB - 1));
        const unsigned col = (unsigned)((en >> RPB_SHIFT) & 0x1FFFFu);
        const float wf = __uint_as_float((unsigned)(en >> 32));
        const unsigned w15 = (unsigned)(wf * 32767.0f + 0.5f);
        const int pos = atomicAdd(&cur[key], 1);
        scw4[pos] = (w15 << 17) | col;
    }
}

// ---------------------------------------------------------------------------
// Pull, feature-half pass: wave = 2 rows x 32 lanes; 4 B entries; 8-wide ILP.
// (R10-proven; at its gather roofline per R8/R12 falsification attempts)
// ---------------------------------------------------------------------------
__global__ __launch_bounds__(256) void pull_half_kernel(
    const int* __restrict__ counts, const int* __restrict__ cur_start,
    const unsigned* __restrict__ scw4, const __half* __restrict__ suph,
    const float* __restrict__ biash, float* __restrict__ outh, int M)
{
    const int wv  = blockIdx.x * 4 + (threadIdx.x >> 6);
    const int row = wv * 2 + ((threadIdx.x >> 5) & 1);
    if (row >= M) return;
    const int l = threadIdx.x & 31;

    const int cnt   = counts[row];
    const int start = cur_start[row];

    float4 acc = *(const float4*)(biash + l * 4);

#define GATHER_FMA_H(pe)                                                      \
    {                                                                         \
        const int   c  = (int)((pe) & 0x1FFFFu);                              \
        const float wj = (float)((pe) >> 17) * (1.0f / 32767.0f);             \
        const uint2 v = *(const uint2*)(suph + (size_t)c * HALF_F + l * 4);   \
        const float2 f0 = __half22float2(*(const __half2*)&v.x);              \
        const float2 f1 = __half22float2(*(const __half2*)&v.y);              \
        acc.x = fmaf(wj, f0.x, acc.x); acc.y = fmaf(wj, f0.y, acc.y);         \
        acc.z = fmaf(wj, f1.x, acc.z); acc.w = fmaf(wj, f1.y, acc.w);         \
    }

    for (int j0 = 0; j0 < cnt; j0 += 32) {
        unsigned pr = 0u;
        if (j0 + l < cnt)
            pr = __builtin_nontemporal_load(scw4 + start + j0 + l);
        const int m = min(32, cnt - j0);

        int j = 0;
        for (; j + 8 <= m; j += 8) {
            const unsigned p0 = __shfl(pr, j, 32),     p1 = __shfl(pr, j + 1, 32);
            const unsigned p2 = __shfl(pr, j + 2, 32), p3 = __shfl(pr, j + 3, 32);
            const unsigned p4 = __shfl(pr, j + 4, 32), p5 = __shfl(pr, j + 5, 32);
            const unsigned p6 = __shfl(pr, j + 6, 32), p7 = __shfl(pr, j + 7, 32);
            GATHER_FMA_H(p0); GATHER_FMA_H(p1); GATHER_FMA_H(p2); GATHER_FMA_H(p3);
            GATHER_FMA_H(p4); GATHER_FMA_H(p5); GATHER_FMA_H(p6); GATHER_FMA_H(p7);
        }
        for (; j < m; ++j) {
            const unsigned p = __shfl(pr, j, 32);
            GATHER_FMA_H(p);
        }
    }
#undef GATHER_FMA_H

    f32x4 o; o[0] = acc.x; o[1] = acc.y; o[2] = acc.z; o[3] = acc.w;
    __builtin_nontemporal_store(o, (f32x4*)(outh + (size_t)row * OUT_F + l * 4));
}

// --------------------------- ws-too-small fallback ---------------------------
__global__ __launch_bounds__(256) void bias_init_kernel(
    float* __restrict__ out, const float* __restrict__ bias, int total4)
{
    const float4* b4 = (const float4*)bias;
    float4* o4 = (float4*)out;
    for (int i = blockIdx.x * blockDim.x + threadIdx.x; i < total4;
         i += gridDim.x * blockDim.x)
        o4[i] = b4[i & 63];
}

__global__ __launch_bounds__(256) void edge_scatter_kernel(
    const int* __restrict__ ei, const float* __restrict__ ew,
    const __half* __restrict__ supA, const __half* __restrict__ supB,
    float* __restrict__ out, int E)
{
    const int e = blockIdx.x * 4 + (threadIdx.x >> 6);
    if (e >= E) return;
    const int lane = threadIdx.x & 63;
    const int   row = ei[e];
    const int   col = ei[E + e];
    const float wgt = ew[e];
    const __half* src = (lane < 32) ? supA : supB;
    const int fl = (lane & 31) * 4;
    const uint2 v = *(const uint2*)(src + (size_t)col * HALF_F + fl);
    const float2 f0 = __half22float2(*(const __half2*)&v.x);
    const float2 f1 = __half22float2(*(const __half2*)&v.y);
    float* o = out + (size_t)row * OUT_F + (lane >> 5) * HALF_F + fl;
    unsafeAtomicAdd(o + 0, wgt * f0.x);
    unsafeAtomicAdd(o + 1, wgt * f0.y);
    unsafeAtomicAdd(o + 2, wgt * f1.x);
    unsafeAtomicAdd(o + 3, wgt * f1.y);
}

// ---------------------------------------------------------------------------
extern "C" void kernel_launch(void* const* d_in, const int* in_sizes, int n_in,
                              void* d_out, int out_size, void* d_ws, size_t ws_size,
                              hipStream_t stream)
{
    const float* x    = (const float*)d_in[0];
    const int*   ei   = (const int*)d_in[1];
    const float* ew   = (const float*)d_in[2];
    const float* w    = (const float*)d_in[3];
    const float* bias = (const float*)d_in[4];
    float* out = (float*)d_out;

    const int M = in_sizes[0] / IN_F;   // 100000
    const int E = in_sizes[2];          // 3,200,000
    const int nbins = (M + RPB - 1) >> RPB_SHIFT;        // 391
    const int T     = (E + TILE_E - 1) / TILE_E;         // 782

    // workspace layout
    char* p = (char*)d_ws;
    const size_t suph_b   = (((size_t)M * HALF_F * sizeof(__half)) + 255) & ~255ull;
    const size_t counts_b = ((size_t)M * 4 + 255) & ~255ull;
    const size_t btot_b   = NBINS_MAX * 4;
    const size_t cstart_b = counts_b;
    const size_t bstart_b = NBINS_MAX * 4;
    const size_t thist_b  = (((size_t)T * NBINS_MAX * 4) + 255) & ~255ull;  // ~1.6 MB
    const size_t scw4_b   = ((size_t)E * 4 + 255) & ~255ull;
    const size_t tscw_b   = ((size_t)E * 8 + 255) & ~255ull;
    const size_t wt_b     = (size_t)IN_F * OUT_F * sizeof(short);
    const size_t need     = 2 * suph_b + counts_b + btot_b + cstart_b
                          + bstart_b + thist_b + scw4_b + tscw_b + wt_b;

    __half*   supA    = (__half*)p;            p += suph_b;
    __half*   supB    = (__half*)p;            p += suph_b;
    int*      counts  = (int*)p;               p += counts_b;
    int*      btot    = (int*)p;               p += btot_b;
    int*      cstart  = (int*)p;               p += cstart_b;
    int*      bstart  = (int*)p;               p += bstart_b;
    int*      thist   = (int*)p;               p += thist_b;
    unsigned* scw4    = (unsigned*)p;          p += scw4_b;
    ull*      tscw    = (ull*)p;               p += tscw_b;
    short*    wtb     = (short*)p;

    // 1) wt = bf16(w^T); supA/B = fp16(x @ W) via LDS-staged MFMA
    convert_wt_kernel<<<(IN_F * OUT_F) / 256, 256, 0, stream>>>(w, wtb);
    mfma_gemm_kernel<<<(M + 31) / 32, 256, 0, stream>>>(x, wtb, supA, supB, M);

    if (ws_size >= need) {
        // 2) CSR build: all bookkeeping in LDS, zero global atomics
        a1a_hist_kernel<<<T, 256, 0, stream>>>(ei, thist, E);
        tile_scan_kernel<<<nbins, 256, 0, stream>>>(thist, btot, T);
        bin_scan_kernel<<<1, NBINS_MAX, 0, stream>>>(btot, bstart, nbins);
        a1b_scatter_kernel<<<T, 256, 0, stream>>>(ei, ew, bstart, thist, tscw, E);
        a2_sort_kernel<<<nbins, 1024, 0, stream>>>(
            tscw, bstart, btot, counts, cstart, scw4, M);
        // 3) pull, two feature-half passes
        const int pblocks = ((M + 1) / 2 + 3) / 4;
        pull_half_kernel<<<pblocks, 256, 0, stream>>>(
            counts, cstart, scw4, supA, bias, out, M);
        pull_half_kernel<<<pblocks, 256, 0, stream>>>(
            counts, cstart, scw4, supB, bias + HALF_F, out + HALF_F, M);
    } else {
        const int total4 = M * OUT_F / 4;
        bias_init_kernel<<<2048, 256, 0, stream>>>(out, bias, total4);
        edge_scatter_kernel<<<(E + 3) / 4, 256, 0, stream>>>(ei, ew, supA, supB, out, E);
    }
}